// Round 11
// baseline (236.672 us; speedup 1.0000x reference)
//
#include <hip/hip_runtime.h>
#include <hip/hip_bf16.h>
#include <cfloat>
#include <math.h>

#define NFULL 4096
#define NPOOL 1024
#define NTOK  5120
#define VDIM  4096

typedef __attribute__((ext_vector_type(8))) short short8;   // 8 bf16 (4 VGPR)
typedef __attribute__((ext_vector_type(4))) float f4;       // MFMA acc
typedef unsigned long long u64;

#define MFMA16(a,b,c) __builtin_amdgcn_mfma_f32_16x16x32_bf16((a),(b),(c),0,0,0)

static __device__ __forceinline__ void gl_lds16(const void* g, void* l) {
    __builtin_amdgcn_global_load_lds(
        (const __attribute__((address_space(1))) unsigned int*)g,
        (__attribute__((address_space(3))) unsigned int*)l, 16, 0, 0);
}

// ==== bf16 MFMA 128x128 core, BK=64, XOR-swizzled LDS (r4-verified) ========
#define BGEMM3_CORE(AM, Bt)                                                    \
    int lane = tid & 63, w = tid >> 6, wy = w >> 1, wx = w & 1;                \
    int lm = lane & 15, quad = lane >> 4;                                      \
    int lr8 = lane >> 3;                                                       \
    int kcs = (lane & 7) ^ lr8;                                                \
    int rS = w * 32 + lr8;                                                     \
    const __hip_bfloat16* Ag = (AM) + (mB + rS) * 512 + kcs * 8;               \
    const __hip_bfloat16* Bg = (Bt) + (nB + rS) * 512 + kcs * 8;               \
    __hip_bfloat16* Al = As + (w * 32) * 64 + lane * 8;                        \
    __hip_bfloat16* Bl = Bs + (w * 32) * 64 + lane * 8;                        \
    f4 acc[4][4];                                                              \
    _Pragma("unroll") for (int i = 0; i < 4; ++i)                              \
        _Pragma("unroll") for (int j = 0; j < 4; ++j)                          \
            acc[i][j] = f4{0.f, 0.f, 0.f, 0.f};                                \
    int aswz = lm & 7;                                                         \
    for (int kt = 0; kt < 8; ++kt) {                                           \
        __syncthreads();                                                       \
        _Pragma("unroll") for (int i = 0; i < 4; ++i) {                        \
            gl_lds16(Ag + kt * 64 + i * 8 * 512, Al + i * 8 * 64);             \
            gl_lds16(Bg + kt * 64 + i * 8 * 512, Bl + i * 8 * 64);             \
        }                                                                      \
        __syncthreads();                                                       \
        _Pragma("unroll") for (int s = 0; s < 2; ++s) {                        \
            short8 aF[4], bF[4];                                               \
            int slot = ((s * 4 + quad) ^ aswz) << 3;                           \
            _Pragma("unroll") for (int mt = 0; mt < 4; ++mt)                   \
                aF[mt] = *(const short8*)(As + (wy * 64 + mt * 16 + lm) * 64 + slot); \
            _Pragma("unroll") for (int nt = 0; nt < 4; ++nt)                   \
                bF[nt] = *(const short8*)(Bs + (wx * 64 + nt * 16 + lm) * 64 + slot); \
            _Pragma("unroll") for (int mt = 0; mt < 4; ++mt)                   \
                _Pragma("unroll") for (int nt = 0; nt < 4; ++nt)               \
                    acc[mt][nt] = MFMA16(aF[mt], bF[nt], acc[mt][nt]);         \
        }                                                                      \
    }

// ======================= prep: transposes + casts + zero-init ==============
__global__ void prep_k(const float* __restrict__ z, const float* __restrict__ cbk,
                       const float* __restrict__ Wq, const float* __restrict__ Wv,
                       float* __restrict__ X, __hip_bfloat16* __restrict__ Xh,
                       __hip_bfloat16* __restrict__ cbh,
                       __hip_bfloat16* __restrict__ WqT, __hip_bfloat16* __restrict__ WvT,
                       u64* __restrict__ packed, unsigned int* __restrict__ Kmax2i) {
    __shared__ float smem[33 * 32];
    int bx = blockIdx.x;
    if (bx < 2048) {
        float (*tile)[33] = (float(*)[33])smem;
        int t0 = (bx & 31) * 32, c0 = ((bx >> 5) & 15) * 32, b = bx >> 9;
        int tx = threadIdx.x & 31, ty = threadIdx.x >> 5;
        #pragma unroll
        for (int i = 0; i < 4; ++i) {
            int c = ty + i * 8;
            tile[c][tx] = z[((b << 9) + c0 + c) * 1024 + t0 + tx];
        }
        __syncthreads();
        #pragma unroll
        for (int i = 0; i < 4; ++i) {
            int tl = ty + i * 8;
            int tok = (b << 10) + t0 + tl;
            Xh[tok * 512 + c0 + tx] = __float2bfloat16(tile[tx][tl]);
        }
        float m = 0.25f * (tile[tx][ty * 4] + tile[tx][ty * 4 + 1] +
                           tile[tx][ty * 4 + 2] + tile[tx][ty * 4 + 3]);
        int tq = (t0 >> 2) + ty;
        X[(NFULL + (b << 8) + tq) * 512 + c0 + tx] = m;
    } else if (bx < 4096) {
        int i0 = (bx - 2048) * 1024 + threadIdx.x * 4;
        float4 v = *(const float4*)(cbk + i0);
        __hip_bfloat16* d = cbh + i0;
        d[0] = __float2bfloat16(v.x); d[1] = __float2bfloat16(v.y);
        d[2] = __float2bfloat16(v.z); d[3] = __float2bfloat16(v.w);
    } else if (bx < 4608) {
        int lin = bx - 4096;
        const float* W = (lin >> 8) ? Wv : Wq;
        __hip_bfloat16* WT = (lin >> 8) ? WvT : WqT;
        float (*t)[33] = (float(*)[33])smem;
        int bk = ((lin >> 4) & 15) * 32, bn = (lin & 15) * 32;
        int lx = threadIdx.x & 31, ly = threadIdx.x >> 5;
        #pragma unroll
        for (int i = 0; i < 4; ++i) {
            int r = ly * 4 + i;
            t[r][lx] = W[(bk + r) * 512 + bn + lx];
        }
        __syncthreads();
        #pragma unroll
        for (int i = 0; i < 4; ++i) {
            int r = ly * 4 + i;
            WT[(bn + r) * 512 + bk + lx] = __float2bfloat16(t[lx][r]);
        }
    } else {
        int i = (bx - 4608) * 256 + threadIdx.x;     // 0..4095
        packed[i] = 0ull;
        if (bx == 4608 && threadIdx.x == 0) Kmax2i[0] = 0u;
    }
}

// ======================= mid1: fp32 proj | pool-c (both depend on prep) ====
// r20: the 8x8 reg-blocked GEMM (structure verified correct r9/r10) spilled
// because a SCALAR float acc[8][8] doesn't survive hipcc's allocator --
// VGPR stuck at 72 with FETCH +10MB of scratch, and launch_bounds(256,2)
// was a no-op (r10: identical 72/26MB).  Fix the REPRESENTATION: hold the
// accumulator as 16 f4 ext-vector objects (acc0[8], acc1[8]) with
// vector-scalar FMAs -- exactly how mid2/logits hold 64-VGPR accumulators
// spill-free at the same block size.  LDS layout/staging/prefetch/split-K
// byte-identical to r18 for attribution.
__global__ __launch_bounds__(256, 2) void mid1_k(
    const __hip_bfloat16* __restrict__ Xh,
    const float* __restrict__ cbk, const float* __restrict__ Xp,
    const float* __restrict__ Wk, const float* __restrict__ Wq,
    const float* __restrict__ Wp, const float* __restrict__ bp,
    float* __restrict__ P0, float* __restrict__ P1,
    float* __restrict__ P2, float* __restrict__ P3,
    float* __restrict__ Cp) {
    __shared__ __align__(16) char smraw[20992];
    int bx = blockIdx.x, tid = threadIdx.x;
    if (bx < 576) {
        // ---------------- fp32 split-K projection, 8x8 reg blocking ---------
        float* AsL = (float*)smraw;              // [16][196] k-major, chunked
        float* BsL = AsL + 16 * 196;             // [16][132]
        const float *A, *B; float* P;
        int arow, prow, nB, kOff, nst;
        if (bx < 512) {
            // codebook rows: split-K=4, K-slice 128, 8 stages
            int part = bx >> 7, rem = bx & 127;
            arow = (rem >> 2) * 128; nB = (rem & 3) * 128;
            prow = arow; kOff = part * 128; nst = 8;
            A = cbk; B = Wk;
            P = (part == 0) ? P0 : (part == 1) ? P1 : (part == 2) ? P2 : P3;
        } else {
            // pooled-Q rows: split-K=2, K-slice 256, 16 stages
            int lin = bx - 512;
            int part = lin >> 5, rem = lin & 31;
            arow = (rem >> 2) * 128; nB = (rem & 3) * 128;
            prow = NFULL + arow; kOff = part * 256; nst = 16;
            A = Xp; B = Wq;
            P = part ? P1 : P0;
        }
        int tx = tid & 15, ty = tid >> 4;        // thread-tile coords
        int am = tid >> 1, akq = (tid & 1) * 8;  // A staging: row am, k-octet
        int br = tid >> 4, bc = (tid & 15) * 8;  // B staging
        const float* Ap = A + (arow + am) * 512 + kOff + akq;
        const float* Bp = B + (kOff + br) * 512 + nB + bc;
        float* Aw = AsL + (am >> 3) * 12 + (am & 7);   // + (akq+i)*196
        float* Bw = BsL + br * 132 + bc;
        f4 acc0[8], acc1[8];
        #pragma unroll
        for (int i = 0; i < 8; ++i) {
            acc0[i] = f4{0.f, 0.f, 0.f, 0.f};
            acc1[i] = f4{0.f, 0.f, 0.f, 0.f};
        }
        float4 a0 = *(const float4*)(Ap);
        float4 a1 = *(const float4*)(Ap + 4);
        float4 b0 = *(const float4*)(Bp);
        float4 b1 = *(const float4*)(Bp + 4);
        const float* Ar = AsL + tx * 12;
        const float* Br = BsL + ty * 8;
        for (int st = 0; st < nst; ++st) {
            __syncthreads();
            Aw[(akq + 0) * 196] = a0.x; Aw[(akq + 1) * 196] = a0.y;
            Aw[(akq + 2) * 196] = a0.z; Aw[(akq + 3) * 196] = a0.w;
            Aw[(akq + 4) * 196] = a1.x; Aw[(akq + 5) * 196] = a1.y;
            Aw[(akq + 6) * 196] = a1.z; Aw[(akq + 7) * 196] = a1.w;
            *(float4*)(Bw)     = b0;
            *(float4*)(Bw + 4) = b1;
            __syncthreads();
            if (st + 1 < nst) {   // prefetch next stage (hidden under compute)
                a0 = *(const float4*)(Ap + (st + 1) * 16);
                a1 = *(const float4*)(Ap + (st + 1) * 16 + 4);
                b0 = *(const float4*)(Bp + (st + 1) * 16 * 512);
                b1 = *(const float4*)(Bp + (st + 1) * 16 * 512 + 4);
            }
            #pragma unroll
            for (int kk = 0; kk < 16; ++kk) {
                f4 av0 = *(const f4*)(Ar + kk * 196);
                f4 av1 = *(const f4*)(Ar + kk * 196 + 4);
                f4 bv0 = *(const f4*)(Br + kk * 132);
                f4 bv1 = *(const f4*)(Br + kk * 132 + 4);
                float a_[8] = {av0.x, av0.y, av0.z, av0.w,
                               av1.x, av1.y, av1.z, av1.w};
                #pragma unroll
                for (int i = 0; i < 8; ++i) {
                    acc0[i] += bv0 * a_[i];
                    acc1[i] += bv1 * a_[i];
                }
            }
        }
        #pragma unroll
        for (int i = 0; i < 8; ++i) {
            int row = prow + tx * 8 + i;
            *(f4*)&P[row * 512 + nB + ty * 8]     = acc0[i];
            *(f4*)&P[row * 512 + nB + ty * 8 + 4] = acc1[i];
        }
    } else {
        // ---------------- head-pool weights Cp ------------------------------
        float* Wl = (float*)smraw;             // 4160 floats: lane stride 65
        for (int i = tid; i < 4096; i += 256) Wl[i + (i >> 6)] = Wp[i];
        __syncthreads();
        int w = tid >> 6, lane = tid & 63;
        int tok = (bx - 576) * 4 + w;          // 0..5119
        float x[8];
        if (tok < NFULL) {
            short8 xv = *(const short8*)(Xh + tok * 512 + lane * 8);
            #pragma unroll
            for (int j = 0; j < 8; ++j)
                x[j] = __uint_as_float(((unsigned)(unsigned short)xv[j]) << 16);
        } else {
            const float* xp = Xp + (tok - NFULL) * 512 + lane * 8;
            float4 a = *(const float4*)xp, b = *(const float4*)(xp + 4);
            x[0] = a.x; x[1] = a.y; x[2] = a.z; x[3] = a.w;
            x[4] = b.x; x[5] = b.y; x[6] = b.z; x[7] = b.w;
        }
        float s[8] = {};
        int base = lane * 65;
        #pragma unroll
        for (int j = 0; j < 8; ++j)
            #pragma unroll
            for (int h = 0; h < 8; ++h)
                s[h] = fmaf(x[j], Wl[base + j * 8 + h], s[h]);
        #pragma unroll
        for (int h = 0; h < 8; ++h)
            #pragma unroll
            for (int o = 32; o > 0; o >>= 1) s[h] += __shfl_xor(s[h], o);
        if (lane == 0) {
            #pragma unroll
            for (int h = 0; h < 8; ++h) Cp[tok * 8 + h] = s[h] + bp[h];
        }
    }
}

// ======================= mid2: bf16 bgemms | split-K norm-finish ===========
// [0,256): MFMA GEMMs.  [256,1536): norm-finish, wave-per-row, 4 rows/blk.
// K rows reduce P0+P1+P2+P3; Q rows reduce P0+P1.  P2 aliases Kn
// (read-before-write per row) -- NO __restrict__ on P2/Kn.
__global__ __launch_bounds__(256) void mid2_k(
    const __hip_bfloat16* __restrict__ Xh, const __hip_bfloat16* __restrict__ WqT,
    const __hip_bfloat16* __restrict__ cbh, const __hip_bfloat16* __restrict__ WvT,
    const float* __restrict__ P0, const float* __restrict__ P1,
    const float* P2, const float* __restrict__ P3,
    const float* __restrict__ bk, const float* __restrict__ bq,
    const float* __restrict__ gk, const float* __restrict__ gq,
    const float* __restrict__ Cp, const float* __restrict__ bvv,
    __hip_bfloat16* __restrict__ Qh, float* __restrict__ Vb,
    float* Kn, __hip_bfloat16* __restrict__ Kh,
    float* __restrict__ Qpool, unsigned int* __restrict__ Kmax2i) {
    __shared__ __align__(16) char smraw[32768];
    int bx = blockIdx.x, tid = threadIdx.x;
    if (bx < 256) {
        int part = bx >> 7, rem = bx & 127;
        int mB = (rem & 31) * 128, nB = (rem >> 5) * 128;
        const __hip_bfloat16* AM = part ? cbh : Xh;
        const __hip_bfloat16* Bt = part ? WvT : WqT;
        __hip_bfloat16* As = (__hip_bfloat16*)smraw;
        __hip_bfloat16* Bs = As + 128 * 64;
        BGEMM3_CORE(AM, Bt)
        if (part == 0) {
            int h = (rem >> 5) * 2 + wx;
            float bb[4], gg[4];
            #pragma unroll
            for (int nt = 0; nt < 4; ++nt) {
                bb[nt] = bq[h * 64 + nt * 16 + lm];
                gg[nt] = gq[nt * 16 + lm];
            }
            #pragma unroll
            for (int mt = 0; mt < 4; ++mt)
                #pragma unroll
                for (int reg = 0; reg < 4; ++reg) {
                    int tok = mB + wy * 64 + mt * 16 + quad * 4 + reg;
                    float vv[4], ss = 0.f;
                    #pragma unroll
                    for (int nt = 0; nt < 4; ++nt) {
                        vv[nt] = acc[mt][nt][reg] + bb[nt];
                        ss = fmaf(vv[nt], vv[nt], ss);
                    }
                    #pragma unroll
                    for (int off = 1; off < 16; off <<= 1) ss += __shfl_xor(ss, off);
                    float sc = rsqrtf(ss * (1.0f / 64.0f) + 1e-5f) *
                               Cp[tok * 8 + h] * 0.04419417382415922f;  // 1/(8*sqrt8)
                    #pragma unroll
                    for (int nt = 0; nt < 4; ++nt)
                        Qh[tok * 512 + h * 64 + nt * 16 + lm] =
                            __float2bfloat16(vv[nt] * sc * gg[nt]);
                }
        } else {
            float bb[4];
            #pragma unroll
            for (int nt = 0; nt < 4; ++nt) bb[nt] = bvv[nB + wx * 64 + nt * 16 + lm];
            #pragma unroll
            for (int mt = 0; mt < 4; ++mt)
                #pragma unroll
                for (int reg = 0; reg < 4; ++reg) {
                    int m = mB + wy * 64 + mt * 16 + quad * 4 + reg;
                    #pragma unroll
                    for (int nt = 0; nt < 4; ++nt)
                        Vb[m * 512 + nB + wx * 64 + nt * 16 + lm] =
                            acc[mt][nt][reg] + bb[nt];
                }
        }
    } else {
        // ---------------- split-K reduce + rmsnorm (wave-per-row) -----------
        int w = tid >> 6, lane = tid & 63;
        int row = (bx - 256) * 4 + w;      // 0..5119
        bool isQ = row >= NFULL;
        const float* bias = isQ ? bq : bk;
        const float* g = isQ ? gq : gk;
        int c0 = lane * 8;                 // 8 contiguous cols per lane
        const float* p0 = P0 + row * 512 + c0;
        const float* p1 = P1 + row * 512 + c0;
        float4 a0 = *(const float4*)p0,  a1 = *(const float4*)(p0 + 4);
        float4 d0 = *(const float4*)p1,  d1 = *(const float4*)(p1 + 4);
        float4 e0 = *(const float4*)(bias + c0), e1 = *(const float4*)(bias + c0 + 4);
        int gi = (lane & 7) * 8;
        float4 g0 = *(const float4*)(g + gi), g1 = *(const float4*)(g + gi + 4);
        float v[8];
        v[0] = a0.x + d0.x + e0.x; v[1] = a0.y + d0.y + e0.y;
        v[2] = a0.z + d0.z + e0.z; v[3] = a0.w + d0.w + e0.w;
        v[4] = a1.x + d1.x + e1.x; v[5] = a1.y + d1.y + e1.y;
        v[6] = a1.z + d1.z + e1.z; v[7] = a1.w + d1.w + e1.w;
        if (!isQ) {                        // K rows: 4-way split-K
            const float* p2 = P2 + row * 512 + c0;
            const float* p3 = P3 + row * 512 + c0;
            float4 x0 = *(const float4*)p2, x1 = *(const float4*)(p2 + 4);
            float4 y0 = *(const float4*)p3, y1 = *(const float4*)(p3 + 4);
            v[0] += x0.x + y0.x; v[1] += x0.y + y0.y;
            v[2] += x0.z + y0.z; v[3] += x0.w + y0.w;
            v[4] += x1.x + y1.x; v[5] += x1.y + y1.y;
            v[6] += x1.z + y1.z; v[7] += x1.w + y1.w;
        }
        // per-head (64-col) sum-of-squares: 8 lanes per head
        float ss = 0.f;
        #pragma unroll
        for (int j = 0; j < 8; ++j) ss = fmaf(v[j], v[j], ss);
        ss += __shfl_xor(ss, 1); ss += __shfl_xor(ss, 2); ss += __shfl_xor(ss, 4);
        float sc = rsqrtf(ss * (1.0f / 64.0f) + 1e-5f);
        float gg[8] = {g0.x, g0.y, g0.z, g0.w, g1.x, g1.y, g1.z, g1.w};
        float o_[8];
        #pragma unroll
        for (int j = 0; j < 8; ++j) o_[j] = v[j] * sc * gg[j];
        if (isQ) {
            float cf = Cp[row * 8 + (lane >> 3)] * 0.04419417382415922f;
            #pragma unroll
            for (int j = 0; j < 8; ++j) o_[j] *= cf;
            float* qp = Qpool + (row - NFULL) * 512 + c0;
            *(float4*)qp       = make_float4(o_[0], o_[1], o_[2], o_[3]);
            *(float4*)(qp + 4) = make_float4(o_[4], o_[5], o_[6], o_[7]);
            __hip_bfloat16 hb[8];
            #pragma unroll
            for (int j = 0; j < 8; ++j) hb[j] = __float2bfloat16(o_[j]);
            *(short8*)(Qh + row * 512 + c0) = *(const short8*)hb;
        } else {
            float* kp = Kn + row * 512 + c0;
            *(float4*)kp       = make_float4(o_[0], o_[1], o_[2], o_[3]);
            *(float4*)(kp + 4) = make_float4(o_[4], o_[5], o_[6], o_[7]);
            __hip_bfloat16 hb[8];
            #pragma unroll
            for (int j = 0; j < 8; ++j) hb[j] = __float2bfloat16(o_[j]);
            *(short8*)(Kh + row * 512 + c0) = *(const short8*)hb;
            float rs = 0.f;
            #pragma unroll
            for (int j = 0; j < 8; ++j) rs = fmaf(o_[j], o_[j], rs);
            #pragma unroll
            for (int o = 32; o > 0; o >>= 1) rs += __shfl_xor(rs, o);
            float* wsum = (float*)smraw;
            if (lane == 0) wsum[w] = rs;
            __syncthreads();
            if (tid == 0) {
                float m01 = fmaxf(wsum[0], wsum[1]);
                float m23 = fmaxf(wsum[2], wsum[3]);
                atomicMax(Kmax2i, __float_as_uint(fmaxf(m01, m23)));
            }
        }
    }
}

// ==== logits over all 5120 tokens ==========================================
// r16: ASYMMETRIC 128x256 tile, BK=64, 512 threads (8 waves, 2m x 4n,
// per-wave 64x64 -> acc[4][4]).  Verified winner (logits left top-5).
__global__ __launch_bounds__(512, 4) void logits_full_k(
    const __hip_bfloat16* __restrict__ Qh, const __hip_bfloat16* __restrict__ Kh,
    u64* __restrict__ packed, __hip_bfloat16* __restrict__ Lp) {
    __shared__ __hip_bfloat16 As[128 * 64];   // 16 KB
    __shared__ __hip_bfloat16 Bs[256 * 64];   // 32 KB
    int tid = threadIdx.x;
    int mB = blockIdx.x * 128, nB = blockIdx.y * 256;   // grid (40, 16)
    int lane = tid & 63, w = tid >> 6;        // 8 waves
    int wy = w >> 2, wx = w & 3;              // wy: m-half (64), wx: n-quarter (64)
    int lm = lane & 15, quad = lane >> 4;
    int lr8 = lane >> 3;
    int kcs = (lane & 7) ^ lr8;               // XOR-swizzled source col-chunk
    const __hip_bfloat16* Ag = Qh + (mB + w * 16 + lr8) * 512 + kcs * 8;
    const __hip_bfloat16* Bg = Kh + (nB + w * 32 + lr8) * 512 + kcs * 8;
    __hip_bfloat16* Al = As + (w * 16) * 64 + lane * 8;
    __hip_bfloat16* Bl = Bs + (w * 32) * 64 + lane * 8;
    f4 acc[4][4];
    #pragma unroll
    for (int i = 0; i < 4; ++i)
        #pragma unroll
        for (int j = 0; j < 4; ++j) acc[i][j] = f4{0.f, 0.f, 0.f, 0.f};
    int aswz = lm & 7;
    for (int kt = 0; kt < 8; ++kt) {
        __syncthreads();
        #pragma unroll
        for (int i = 0; i < 2; ++i)           // A: 8 waves x 16 rows = 128
            gl_lds16(Ag + kt * 64 + i * 8 * 512, Al + i * 8 * 64);
        #pragma unroll
        for (int i = 0; i < 4; ++i)           // B: 8 waves x 32 rows = 256
            gl_lds16(Bg + kt * 64 + i * 8 * 512, Bl + i * 8 * 64);
        __syncthreads();
        #pragma unroll
        for (int s = 0; s < 2; ++s) {
            short8 aF[4], bF[4];
            int slot = ((s * 4 + quad) ^ aswz) << 3;
            #pragma unroll
            for (int mt = 0; mt < 4; ++mt)
                aF[mt] = *(const short8*)(As + (wy * 64 + mt * 16 + lm) * 64 + slot);
            #pragma unroll
            for (int nt = 0; nt < 4; ++nt)
                bF[nt] = *(const short8*)(Bs + (wx * 64 + nt * 16 + lm) * 64 + slot);
            #pragma unroll
            for (int mt = 0; mt < 4; ++mt)
                #pragma unroll
                for (int nt = 0; nt < 4; ++nt)
                    acc[mt][nt] = MFMA16(aF[mt], bF[nt], acc[mt][nt]);
        }
    }
    if (blockIdx.x < 32) {
        // full-token rows: packed atomic argmax
        #pragma unroll
        for (int mt = 0; mt < 4; ++mt)
            #pragma unroll
            for (int reg = 0; reg < 4; ++reg) {
                float bv = -FLT_MAX; int bi = 0;
                #pragma unroll
                for (int nt = 0; nt < 4; ++nt) {
                    float v = acc[mt][nt][reg];
                    int n = nB + wx * 64 + nt * 16 + lm;
                    if (v > bv) { bv = v; bi = n; }
                }
                #pragma unroll
                for (int off = 1; off < 16; off <<= 1) {
                    float ov = __shfl_xor(bv, off);
                    int oi = __shfl_xor(bi, off);
                    if (ov > bv || (ov == bv && oi < bi)) { bv = ov; bi = oi; }
                }
                if (lm == 0) {
                    unsigned ub = __float_as_uint(bv);
                    ub = (ub & 0x80000000u) ? ~ub : (ub | 0x80000000u);
                    u64 key = ((u64)ub << 32) | (u64)(0xFFFFFFFFu - (unsigned)bi);
                    int tok = mB + wy * 64 + mt * 16 + quad * 4 + reg;
                    atomicMax(&packed[tok], key);
                }
            }
    } else {
        // pooled rows: bf16 logit rows for candidate rescore
        #pragma unroll
        for (int mt = 0; mt < 4; ++mt)
            #pragma unroll
            for (int reg = 0; reg < 4; ++reg) {
                int tok = mB + wy * 64 + mt * 16 + quad * 4 + reg;
                long long base = (long long)(tok - NFULL) * 4096;
                #pragma unroll
                for (int nt = 0; nt < 4; ++nt)
                    Lp[base + nB + wx * 64 + nt * 16 + lm] =
                        __float2bfloat16(acc[mt][nt][reg]);
            }
    }
}

// ======================= tail: rescore | hist+perplexity ===================
__global__ __launch_bounds__(256) void tail_k(
    const float* __restrict__ Qpool, const float* __restrict__ Kn,
    const __hip_bfloat16* __restrict__ Lp, const unsigned int* __restrict__ Kmax2i,
    const u64* __restrict__ packed, int* __restrict__ codeP,
    float* __restrict__ outPpl) {
    __shared__ int cnt[4096];
    __shared__ float red[4];
    int tid = threadIdx.x;
    if (blockIdx.x < 256) {
        int wid = tid >> 6, lane = tid & 63;
        int tok = blockIdx.x * 4 + wid;
        const float* q = Qpool + tok * 512;
        float4 q0 = *(const float4*)(q + lane * 8);
        float4 q1 = *(const float4*)(q + lane * 8 + 4);
        float qs = q0.x * q0.x + q0.y * q0.y + q0.z * q0.z + q0.w * q0.w +
                   q1.x * q1.x + q1.y * q1.y + q1.z * q1.z + q1.w * q1.w;
        #pragma unroll
        for (int o = 32; o > 0; o >>= 1) qs += __shfl_xor(qs, o);
        float delta = 0.0078125f * sqrtf(qs) * sqrtf(__uint_as_float(*Kmax2i));
        const __hip_bfloat16* row = Lp + (long long)tok * 4096;
        float mx = -FLT_MAX;
        for (int c = 0; c < 64; ++c)
            mx = fmaxf(mx, __bfloat162float(row[c * 64 + lane]));
        #pragma unroll
        for (int o = 32; o > 0; o >>= 1) mx = fmaxf(mx, __shfl_xor(mx, o));
        float thr = mx - delta;
        float bv = -FLT_MAX; int bi = 0;
        for (int c = 0; c < 64; ++c) {
            float v = __bfloat162float(row[c * 64 + lane]);
            u64 mask = __ballot(v >= thr);
            while (mask) {
                int l = __ffsll((long long)mask) - 1;
                mask &= mask - 1;
                int n = c * 64 + l;
                const float* k = Kn + n * 512;
                float4 k0 = *(const float4*)(k + lane * 8);
                float4 k1 = *(const float4*)(k + lane * 8 + 4);
                float d = q0.x * k0.x;
                d = fmaf(q0.y, k0.y, d); d = fmaf(q0.z, k0.z, d); d = fmaf(q0.w, k0.w, d);
                d = fmaf(q1.x, k1.x, d); d = fmaf(q1.y, k1.y, d);
                d = fmaf(q1.z, k1.z, d); d = fmaf(q1.w, k1.w, d);
                #pragma unroll
                for (int o = 32; o > 0; o >>= 1) d += __shfl_xor(d, o);
                if (d > bv) { bv = d; bi = n; }   // ascending n => first-max wins
            }
        }
        if (lane == 0) codeP[tok] = bi;
    } else {
        for (int i = tid; i < 4096; i += 256) cnt[i] = 0;
        __syncthreads();
        for (int i = tid; i < 4096; i += 256) {
            int bi = (int)(0xFFFFFFFFu - (unsigned)(packed[i] & 0xFFFFFFFFu));
            atomicAdd(&cnt[bi], 1);
        }
        __syncthreads();
        float s = 0.f;
        for (int i = tid; i < 4096; i += 256) {
            float p = (float)cnt[i] * (1.0f / 4096.0f);
            s += p * logf(p + 1e-7f);
        }
        #pragma unroll
        for (int o = 32; o > 0; o >>= 1) s += __shfl_xor(s, o);
        if ((tid & 63) == 0) red[tid >> 6] = s;
        __syncthreads();
        if (tid == 0)
            outPpl[0] = expf(-(red[0] + red[1] + red[2] + red[3]));
    }
}

// ======================= z_hat: wave per (b, j) ============================
__global__ void zhat_k(const float* __restrict__ Vv, const int* __restrict__ codeP,
                       float* __restrict__ out) {
    int w = (blockIdx.x << 2) + (threadIdx.x >> 6);   // 0..1023
    int lane = threadIdx.x & 63;
    int b = w >> 8, j = w & 255;
    const int* cb = codeP + (b << 8);
    const float* rm = Vv + cb[max(j - 1, 0)] * 512;
    const float* r0 = Vv + cb[j] * 512;
    const float* rp = Vv + cb[min(j + 1, 255)] * 512;
    #pragma unroll
    for (int i = 0; i < 8; ++i) {
        int c = i * 64 + lane;
        float vm = rm[c], v0 = r0[c], vp = rp[c];
        float4 o;
        o.x = 0.375f * vm + 0.625f * v0;
        o.y = 0.125f * vm + 0.875f * v0;
        o.z = 0.875f * v0 + 0.125f * vp;
        o.w = 0.625f * v0 + 0.375f * vp;
        *(float4*)&out[(((b << 9) + c) << 10) + (j << 2)] = o;
    }
}

extern "C" void kernel_launch(void* const* d_in, const int* in_sizes, int n_in,
                              void* d_out, int out_size, void* d_ws, size_t ws_size,
                              hipStream_t stream) {
    const float* z   = (const float*)d_in[0];
    const float* cbk = (const float*)d_in[2];
    const float* Wq  = (const float*)d_in[3];
    const float* bq  = (const float*)d_in[4];
    const float* Wk  = (const float*)d_in[5];
    const float* bk  = (const float*)d_in[6];
    const float* Wv  = (const float*)d_in[7];
    const float* bv  = (const float*)d_in[8];
    const float* Wp  = (const float*)d_in[9];
    const float* bp  = (const float*)d_in[10];
    const float* gq  = (const float*)d_in[11];
    const float* gk  = (const float*)d_in[12];
    float* out = (float*)d_out;

    // ---- workspace layout ----
    float* X      = (float*)d_ws;            // 5120*512 (rows 0..4095 = P3 alias)
    float* Qpool  = X + 5120 * 512;          // 1024*512
    float* Kn     = Qpool + 1024 * 512;      // 4096*512 (doubles as P2)
    float* Vb     = Kn + 4096 * 512;         // 4096*512
    float* Cp     = Vb + 4096 * 512;         // 5120*8
    float* P0     = Cp + 5120 * 8;           // 5120*512 (aliased by Lp later)
    float* P1     = P0 + 5120 * 512;         // 5120*512
    u64*   packed = (u64*)(P1 + 5120 * 512); // 4096
    unsigned int* Kmax2i = (unsigned int*)(packed + 4096);  // 4
    int*   codeP  = (int*)(Kmax2i + 4);      // 1024
    __hip_bfloat16* Qh  = (__hip_bfloat16*)(codeP + 1024);  // 5120*512
    __hip_bfloat16* Kh  = Qh + 5120 * 512;   // 4096*512
    __hip_bfloat16* Xh  = Kh + 4096 * 512;   // 4096*512
    __hip_bfloat16* cbh = Xh + 4096 * 512;   // 4096*512
    __hip_bfloat16* WqT = cbh + 4096 * 512;  // 512*512
    __hip_bfloat16* WvT = WqT + 512 * 512;   // 512*512
    __hip_bfloat16* Lp  = (__hip_bfloat16*)P0;  // alias: 1024*4096 bf16
    float* P2 = Kn;                          // alias: K-rows only (0..4095)
    float* P3 = X;                           // alias: X rows 0..4095 are dead

    prep_k<<<4624, 256, 0, stream>>>(z, cbk, Wq, Wv, X, Xh, cbh, WqT, WvT,
                                     packed, Kmax2i);
    mid1_k<<<1856, 256, 0, stream>>>(Xh, cbk, X + 4096 * 512, Wk, Wq, Wp, bp,
                                     P0, P1, P2, P3, Cp);
    mid2_k<<<1536, 256, 0, stream>>>(Xh, WqT, cbh, WvT, P0, P1, P2, P3,
                                     bk, bq, gk, gq, Cp, bv,
                                     Qh, Vb, Kn, Kh, Qpool, Kmax2i);
    logits_full_k<<<dim3(40, 16), 512, 0, stream>>>(Qh, Kh, packed, Lp);
    tail_k<<<257, 256, 0, stream>>>(Qpool, Kn, Lp, Kmax2i, packed, codeP,
                                    out + 4 * 512 * 1024);
    zhat_k<<<256, 256, 0, stream>>>(Vb, codeP, out);
}

// Round 12
// 220.383 us; speedup vs baseline: 1.0739x; 1.0739x over previous
//
#include <hip/hip_runtime.h>
#include <hip/hip_bf16.h>
#include <cfloat>
#include <math.h>

#define NFULL 4096
#define NPOOL 1024
#define NTOK  5120
#define VDIM  4096

typedef __attribute__((ext_vector_type(8))) short short8;   // 8 bf16 (4 VGPR)
typedef __attribute__((ext_vector_type(4))) float f4;       // MFMA acc
typedef unsigned long long u64;

#define MFMA16(a,b,c) __builtin_amdgcn_mfma_f32_16x16x32_bf16((a),(b),(c),0,0,0)

static __device__ __forceinline__ void gl_lds16(const void* g, void* l) {
    __builtin_amdgcn_global_load_lds(
        (const __attribute__((address_space(1))) unsigned int*)g,
        (__attribute__((address_space(3))) unsigned int*)l, 16, 0, 0);
}

// ==== bf16 MFMA 128x128 core, BK=64, XOR-swizzled LDS (r4-verified) ========
#define BGEMM3_CORE(AM, Bt)                                                    \
    int lane = tid & 63, w = tid >> 6, wy = w >> 1, wx = w & 1;                \
    int lm = lane & 15, quad = lane >> 4;                                      \
    int lr8 = lane >> 3;                                                       \
    int kcs = (lane & 7) ^ lr8;                                                \
    int rS = w * 32 + lr8;                                                     \
    const __hip_bfloat16* Ag = (AM) + (mB + rS) * 512 + kcs * 8;               \
    const __hip_bfloat16* Bg = (Bt) + (nB + rS) * 512 + kcs * 8;               \
    __hip_bfloat16* Al = As + (w * 32) * 64 + lane * 8;                        \
    __hip_bfloat16* Bl = Bs + (w * 32) * 64 + lane * 8;                        \
    f4 acc[4][4];                                                              \
    _Pragma("unroll") for (int i = 0; i < 4; ++i)                              \
        _Pragma("unroll") for (int j = 0; j < 4; ++j)                          \
            acc[i][j] = f4{0.f, 0.f, 0.f, 0.f};                                \
    int aswz = lm & 7;                                                         \
    for (int kt = 0; kt < 8; ++kt) {                                           \
        __syncthreads();                                                       \
        _Pragma("unroll") for (int i = 0; i < 4; ++i) {                        \
            gl_lds16(Ag + kt * 64 + i * 8 * 512, Al + i * 8 * 64);             \
            gl_lds16(Bg + kt * 64 + i * 8 * 512, Bl + i * 8 * 64);             \
        }                                                                      \
        __syncthreads();                                                       \
        _Pragma("unroll") for (int s = 0; s < 2; ++s) {                        \
            short8 aF[4], bF[4];                                               \
            int slot = ((s * 4 + quad) ^ aswz) << 3;                           \
            _Pragma("unroll") for (int mt = 0; mt < 4; ++mt)                   \
                aF[mt] = *(const short8*)(As + (wy * 64 + mt * 16 + lm) * 64 + slot); \
            _Pragma("unroll") for (int nt = 0; nt < 4; ++nt)                   \
                bF[nt] = *(const short8*)(Bs + (wx * 64 + nt * 16 + lm) * 64 + slot); \
            _Pragma("unroll") for (int mt = 0; mt < 4; ++mt)                   \
                _Pragma("unroll") for (int nt = 0; nt < 4; ++nt)               \
                    acc[mt][nt] = MFMA16(aF[mt], bF[nt], acc[mt][nt]);         \
        }                                                                      \
    }

// ======================= prep: transposes + casts + zero-init ==============
__global__ void prep_k(const float* __restrict__ z, const float* __restrict__ cbk,
                       const float* __restrict__ Wq, const float* __restrict__ Wv,
                       float* __restrict__ X, __hip_bfloat16* __restrict__ Xh,
                       __hip_bfloat16* __restrict__ cbh,
                       __hip_bfloat16* __restrict__ WqT, __hip_bfloat16* __restrict__ WvT,
                       u64* __restrict__ packed, unsigned int* __restrict__ Kmax2i) {
    __shared__ float smem[33 * 32];
    int bx = blockIdx.x;
    if (bx < 2048) {
        float (*tile)[33] = (float(*)[33])smem;
        int t0 = (bx & 31) * 32, c0 = ((bx >> 5) & 15) * 32, b = bx >> 9;
        int tx = threadIdx.x & 31, ty = threadIdx.x >> 5;
        #pragma unroll
        for (int i = 0; i < 4; ++i) {
            int c = ty + i * 8;
            tile[c][tx] = z[((b << 9) + c0 + c) * 1024 + t0 + tx];
        }
        __syncthreads();
        #pragma unroll
        for (int i = 0; i < 4; ++i) {
            int tl = ty + i * 8;
            int tok = (b << 10) + t0 + tl;
            Xh[tok * 512 + c0 + tx] = __float2bfloat16(tile[tx][tl]);
        }
        float m = 0.25f * (tile[tx][ty * 4] + tile[tx][ty * 4 + 1] +
                           tile[tx][ty * 4 + 2] + tile[tx][ty * 4 + 3]);
        int tq = (t0 >> 2) + ty;
        X[(NFULL + (b << 8) + tq) * 512 + c0 + tx] = m;
    } else if (bx < 4096) {
        int i0 = (bx - 2048) * 1024 + threadIdx.x * 4;
        float4 v = *(const float4*)(cbk + i0);
        __hip_bfloat16* d = cbh + i0;
        d[0] = __float2bfloat16(v.x); d[1] = __float2bfloat16(v.y);
        d[2] = __float2bfloat16(v.z); d[3] = __float2bfloat16(v.w);
    } else if (bx < 4608) {
        int lin = bx - 4096;
        const float* W = (lin >> 8) ? Wv : Wq;
        __hip_bfloat16* WT = (lin >> 8) ? WvT : WqT;
        float (*t)[33] = (float(*)[33])smem;
        int bk = ((lin >> 4) & 15) * 32, bn = (lin & 15) * 32;
        int lx = threadIdx.x & 31, ly = threadIdx.x >> 5;
        #pragma unroll
        for (int i = 0; i < 4; ++i) {
            int r = ly * 4 + i;
            t[r][lx] = W[(bk + r) * 512 + bn + lx];
        }
        __syncthreads();
        #pragma unroll
        for (int i = 0; i < 4; ++i) {
            int r = ly * 4 + i;
            WT[(bn + r) * 512 + bk + lx] = __float2bfloat16(t[lx][r]);
        }
    } else {
        int i = (bx - 4608) * 256 + threadIdx.x;     // 0..4095
        packed[i] = 0ull;
        if (bx == 4608 && threadIdx.x == 0) Kmax2i[0] = 0u;
    }
}

// ======================= mid1: fp32 proj | pool-c (both depend on prep) ====
// r17 (PROVEN BEST, restored): (a) loop-rotated prefetch; (b) split-K=4 for
// codebook rows (1024 blocks) + split-K=2 for Q rows (128) -> 4.5 blocks/CU.
// P2==Kn, P3==X-rows-0..4095 aliases (verified r8).  The r18-r20 8x8
// reg-blocked variants all failed: hipcc refuses to allocate a 64-VGPR
// non-MFMA accumulator at this shape (VGPR pinned 64-72, scratch spill,
// FETCH +10MB) across scalar-array, launch-bounds(256,2), and f4-vector
// representations.  4x8 is the allocator-compatible form; measured 47.6us,
// VALUBusy 43% (LDS-pipe model floor ~38us -- gap unreachable here).
__global__ __launch_bounds__(256) void mid1_k(
    const __hip_bfloat16* __restrict__ Xh,
    const float* __restrict__ cbk, const float* __restrict__ Xp,
    const float* __restrict__ Wk, const float* __restrict__ Wq,
    const float* __restrict__ Wp, const float* __restrict__ bp,
    float* __restrict__ P0, float* __restrict__ P1,
    float* __restrict__ P2, float* __restrict__ P3,
    float* __restrict__ Cp) {
    __shared__ __align__(16) char smraw[16640];
    int bx = blockIdx.x, tid = threadIdx.x;
    if (bx < 1152) {
        // ---------------- fp32 split-K projection ---------------------------
        float (*As2)[68]  = (float(*)[68])smraw;
        float (*Bs2)[132] = (float(*)[132])(smraw + 16 * 68 * 4);
        const float *A, *B; float* P;
        int mB, nB, kOff, nkt;
        if (bx < 1024) {
            // codebook rows: split-K=4, K-slice 128, 8 kt
            int part = bx >> 8, rem = bx & 255;
            mB = (rem & 63) * 64; nB = (rem >> 6) * 128;
            kOff = part * 128; nkt = 8;
            A = cbk + mB * 512; B = Wk;
            P = (part == 0) ? P0 : (part == 1) ? P1 : (part == 2) ? P2 : P3;
        } else {
            // pooled-Q rows: split-K=2, K-slice 256, 16 kt
            int lin = bx - 1024;
            int part = lin >> 6, rem = lin & 63;
            mB = NFULL + (rem & 15) * 64; nB = (rem >> 4) * 128;
            kOff = part * 256; nkt = 16;
            A = Xp + (rem & 15) * 64 * 512; B = Wq;
            P = part ? P1 : P0;
        }
        int ty = tid >> 4, tx = tid & 15;
        int arow = tid >> 2, achk = tid & 3;
        int brow = tid >> 4, bcol = (tid & 15) * 4;
        const float* Ap = A + arow * 512 + kOff + achk * 4;
        const float* Bp = B + (kOff + brow) * 512 + nB + bcol;
        float acc[4][8] = {};
        float4 a  = *(const float4*)(Ap);
        float4 b0 = *(const float4*)(Bp);
        float4 b1 = *(const float4*)(Bp + 64);
        for (int kt = 0; kt < nkt; ++kt) {
            __syncthreads();
            As2[achk * 4 + 0][arow] = a.x; As2[achk * 4 + 1][arow] = a.y;
            As2[achk * 4 + 2][arow] = a.z; As2[achk * 4 + 3][arow] = a.w;
            *(float4*)&Bs2[brow][bcol]      = b0;
            *(float4*)&Bs2[brow][bcol + 64] = b1;
            __syncthreads();
            if (kt + 1 < nkt) {   // prefetch kt+1 -- hidden under 16-kk compute
                a  = *(const float4*)(Ap + (kt + 1) * 16);
                b0 = *(const float4*)(Bp + (kt + 1) * 16 * 512);
                b1 = *(const float4*)(Bp + (kt + 1) * 16 * 512 + 64);
            }
            #pragma unroll
            for (int kk = 0; kk < 16; ++kk) {
                float4 av  = *(const float4*)&As2[kk][ty * 4];
                float4 bv0 = *(const float4*)&Bs2[kk][tx * 4];
                float4 bv1 = *(const float4*)&Bs2[kk][64 + tx * 4];
                float a4[4] = {av.x, av.y, av.z, av.w};
                float b8[8] = {bv0.x, bv0.y, bv0.z, bv0.w, bv1.x, bv1.y, bv1.z, bv1.w};
                #pragma unroll
                for (int i = 0; i < 4; ++i)
                    #pragma unroll
                    for (int j = 0; j < 8; ++j)
                        acc[i][j] = fmaf(a4[i], b8[j], acc[i][j]);
            }
        }
        #pragma unroll
        for (int i = 0; i < 4; ++i) {
            int row = mB + ty * 4 + i;
            float4 r0, r1;
            r0.x = acc[i][0]; r0.y = acc[i][1]; r0.z = acc[i][2]; r0.w = acc[i][3];
            r1.x = acc[i][4]; r1.y = acc[i][5]; r1.z = acc[i][6]; r1.w = acc[i][7];
            *(float4*)&P[row * 512 + nB + tx * 4]      = r0;
            *(float4*)&P[row * 512 + nB + 64 + tx * 4] = r1;
        }
    } else {
        // ---------------- head-pool weights Cp ------------------------------
        float* Wl = (float*)smraw;             // 4160 floats: lane stride 65
        for (int i = tid; i < 4096; i += 256) Wl[i + (i >> 6)] = Wp[i];
        __syncthreads();
        int w = tid >> 6, lane = tid & 63;
        int tok = (bx - 1152) * 4 + w;         // 0..5119
        float x[8];
        if (tok < NFULL) {
            short8 xv = *(const short8*)(Xh + tok * 512 + lane * 8);
            #pragma unroll
            for (int j = 0; j < 8; ++j)
                x[j] = __uint_as_float(((unsigned)(unsigned short)xv[j]) << 16);
        } else {
            const float* xp = Xp + (tok - NFULL) * 512 + lane * 8;
            float4 a = *(const float4*)xp, b = *(const float4*)(xp + 4);
            x[0] = a.x; x[1] = a.y; x[2] = a.z; x[3] = a.w;
            x[4] = b.x; x[5] = b.y; x[6] = b.z; x[7] = b.w;
        }
        float s[8] = {};
        int base = lane * 65;
        #pragma unroll
        for (int j = 0; j < 8; ++j)
            #pragma unroll
            for (int h = 0; h < 8; ++h)
                s[h] = fmaf(x[j], Wl[base + j * 8 + h], s[h]);
        #pragma unroll
        for (int h = 0; h < 8; ++h)
            #pragma unroll
            for (int o = 32; o > 0; o >>= 1) s[h] += __shfl_xor(s[h], o);
        if (lane == 0) {
            #pragma unroll
            for (int h = 0; h < 8; ++h) Cp[tok * 8 + h] = s[h] + bp[h];
        }
    }
}

// ======================= mid2: bf16 bgemms | split-K norm-finish ===========
// [0,256): MFMA GEMMs.  [256,1536): norm-finish, wave-per-row, 4 rows/blk.
// K rows reduce P0+P1+P2+P3; Q rows reduce P0+P1.  P2 aliases Kn
// (read-before-write per row) -- NO __restrict__ on P2/Kn.
__global__ __launch_bounds__(256) void mid2_k(
    const __hip_bfloat16* __restrict__ Xh, const __hip_bfloat16* __restrict__ WqT,
    const __hip_bfloat16* __restrict__ cbh, const __hip_bfloat16* __restrict__ WvT,
    const float* __restrict__ P0, const float* __restrict__ P1,
    const float* P2, const float* __restrict__ P3,
    const float* __restrict__ bk, const float* __restrict__ bq,
    const float* __restrict__ gk, const float* __restrict__ gq,
    const float* __restrict__ Cp, const float* __restrict__ bvv,
    __hip_bfloat16* __restrict__ Qh, float* __restrict__ Vb,
    float* Kn, __hip_bfloat16* __restrict__ Kh,
    float* __restrict__ Qpool, unsigned int* __restrict__ Kmax2i) {
    __shared__ __align__(16) char smraw[32768];
    int bx = blockIdx.x, tid = threadIdx.x;
    if (bx < 256) {
        int part = bx >> 7, rem = bx & 127;
        int mB = (rem & 31) * 128, nB = (rem >> 5) * 128;
        const __hip_bfloat16* AM = part ? cbh : Xh;
        const __hip_bfloat16* Bt = part ? WvT : WqT;
        __hip_bfloat16* As = (__hip_bfloat16*)smraw;
        __hip_bfloat16* Bs = As + 128 * 64;
        BGEMM3_CORE(AM, Bt)
        if (part == 0) {
            int h = (rem >> 5) * 2 + wx;
            float bb[4], gg[4];
            #pragma unroll
            for (int nt = 0; nt < 4; ++nt) {
                bb[nt] = bq[h * 64 + nt * 16 + lm];
                gg[nt] = gq[nt * 16 + lm];
            }
            #pragma unroll
            for (int mt = 0; mt < 4; ++mt)
                #pragma unroll
                for (int reg = 0; reg < 4; ++reg) {
                    int tok = mB + wy * 64 + mt * 16 + quad * 4 + reg;
                    float vv[4], ss = 0.f;
                    #pragma unroll
                    for (int nt = 0; nt < 4; ++nt) {
                        vv[nt] = acc[mt][nt][reg] + bb[nt];
                        ss = fmaf(vv[nt], vv[nt], ss);
                    }
                    #pragma unroll
                    for (int off = 1; off < 16; off <<= 1) ss += __shfl_xor(ss, off);
                    float sc = rsqrtf(ss * (1.0f / 64.0f) + 1e-5f) *
                               Cp[tok * 8 + h] * 0.04419417382415922f;  // 1/(8*sqrt8)
                    #pragma unroll
                    for (int nt = 0; nt < 4; ++nt)
                        Qh[tok * 512 + h * 64 + nt * 16 + lm] =
                            __float2bfloat16(vv[nt] * sc * gg[nt]);
                }
        } else {
            float bb[4];
            #pragma unroll
            for (int nt = 0; nt < 4; ++nt) bb[nt] = bvv[nB + wx * 64 + nt * 16 + lm];
            #pragma unroll
            for (int mt = 0; mt < 4; ++mt)
                #pragma unroll
                for (int reg = 0; reg < 4; ++reg) {
                    int m = mB + wy * 64 + mt * 16 + quad * 4 + reg;
                    #pragma unroll
                    for (int nt = 0; nt < 4; ++nt)
                        Vb[m * 512 + nB + wx * 64 + nt * 16 + lm] =
                            acc[mt][nt][reg] + bb[nt];
                }
        }
    } else {
        // ---------------- split-K reduce + rmsnorm (wave-per-row) -----------
        int w = tid >> 6, lane = tid & 63;
        int row = (bx - 256) * 4 + w;      // 0..5119
        bool isQ = row >= NFULL;
        const float* bias = isQ ? bq : bk;
        const float* g = isQ ? gq : gk;
        int c0 = lane * 8;                 // 8 contiguous cols per lane
        const float* p0 = P0 + row * 512 + c0;
        const float* p1 = P1 + row * 512 + c0;
        float4 a0 = *(const float4*)p0,  a1 = *(const float4*)(p0 + 4);
        float4 d0 = *(const float4*)p1,  d1 = *(const float4*)(p1 + 4);
        float4 e0 = *(const float4*)(bias + c0), e1 = *(const float4*)(bias + c0 + 4);
        int gi = (lane & 7) * 8;
        float4 g0 = *(const float4*)(g + gi), g1 = *(const float4*)(g + gi + 4);
        float v[8];
        v[0] = a0.x + d0.x + e0.x; v[1] = a0.y + d0.y + e0.y;
        v[2] = a0.z + d0.z + e0.z; v[3] = a0.w + d0.w + e0.w;
        v[4] = a1.x + d1.x + e1.x; v[5] = a1.y + d1.y + e1.y;
        v[6] = a1.z + d1.z + e1.z; v[7] = a1.w + d1.w + e1.w;
        if (!isQ) {                        // K rows: 4-way split-K
            const float* p2 = P2 + row * 512 + c0;
            const float* p3 = P3 + row * 512 + c0;
            float4 x0 = *(const float4*)p2, x1 = *(const float4*)(p2 + 4);
            float4 y0 = *(const float4*)p3, y1 = *(const float4*)(p3 + 4);
            v[0] += x0.x + y0.x; v[1] += x0.y + y0.y;
            v[2] += x0.z + y0.z; v[3] += x0.w + y0.w;
            v[4] += x1.x + y1.x; v[5] += x1.y + y1.y;
            v[6] += x1.z + y1.z; v[7] += x1.w + y1.w;
        }
        // per-head (64-col) sum-of-squares: 8 lanes per head
        float ss = 0.f;
        #pragma unroll
        for (int j = 0; j < 8; ++j) ss = fmaf(v[j], v[j], ss);
        ss += __shfl_xor(ss, 1); ss += __shfl_xor(ss, 2); ss += __shfl_xor(ss, 4);
        float sc = rsqrtf(ss * (1.0f / 64.0f) + 1e-5f);
        float gg[8] = {g0.x, g0.y, g0.z, g0.w, g1.x, g1.y, g1.z, g1.w};
        float o_[8];
        #pragma unroll
        for (int j = 0; j < 8; ++j) o_[j] = v[j] * sc * gg[j];
        if (isQ) {
            float cf = Cp[row * 8 + (lane >> 3)] * 0.04419417382415922f;
            #pragma unroll
            for (int j = 0; j < 8; ++j) o_[j] *= cf;
            float* qp = Qpool + (row - NFULL) * 512 + c0;
            *(float4*)qp       = make_float4(o_[0], o_[1], o_[2], o_[3]);
            *(float4*)(qp + 4) = make_float4(o_[4], o_[5], o_[6], o_[7]);
            __hip_bfloat16 hb[8];
            #pragma unroll
            for (int j = 0; j < 8; ++j) hb[j] = __float2bfloat16(o_[j]);
            *(short8*)(Qh + row * 512 + c0) = *(const short8*)hb;
        } else {
            float* kp = Kn + row * 512 + c0;
            *(float4*)kp       = make_float4(o_[0], o_[1], o_[2], o_[3]);
            *(float4*)(kp + 4) = make_float4(o_[4], o_[5], o_[6], o_[7]);
            __hip_bfloat16 hb[8];
            #pragma unroll
            for (int j = 0; j < 8; ++j) hb[j] = __float2bfloat16(o_[j]);
            *(short8*)(Kh + row * 512 + c0) = *(const short8*)hb;
            float rs = 0.f;
            #pragma unroll
            for (int j = 0; j < 8; ++j) rs = fmaf(o_[j], o_[j], rs);
            #pragma unroll
            for (int o = 32; o > 0; o >>= 1) rs += __shfl_xor(rs, o);
            float* wsum = (float*)smraw;
            if (lane == 0) wsum[w] = rs;
            __syncthreads();
            if (tid == 0) {
                float m01 = fmaxf(wsum[0], wsum[1]);
                float m23 = fmaxf(wsum[2], wsum[3]);
                atomicMax(Kmax2i, __float_as_uint(fmaxf(m01, m23)));
            }
        }
    }
}

// ==== logits over all 5120 tokens ==========================================
// r16: ASYMMETRIC 128x256 tile, BK=64, 512 threads (8 waves, 2m x 4n,
// per-wave 64x64 -> acc[4][4]).  0.75x staged bytes of 128^2 at the SAME
// 2-blocks/CU residency (48 KB LDS).  Verified winner (logits left top-5).
__global__ __launch_bounds__(512, 4) void logits_full_k(
    const __hip_bfloat16* __restrict__ Qh, const __hip_bfloat16* __restrict__ Kh,
    u64* __restrict__ packed, __hip_bfloat16* __restrict__ Lp) {
    __shared__ __hip_bfloat16 As[128 * 64];   // 16 KB
    __shared__ __hip_bfloat16 Bs[256 * 64];   // 32 KB
    int tid = threadIdx.x;
    int mB = blockIdx.x * 128, nB = blockIdx.y * 256;   // grid (40, 16)
    int lane = tid & 63, w = tid >> 6;        // 8 waves
    int wy = w >> 2, wx = w & 3;              // wy: m-half (64), wx: n-quarter (64)
    int lm = lane & 15, quad = lane >> 4;
    int lr8 = lane >> 3;
    int kcs = (lane & 7) ^ lr8;               // XOR-swizzled source col-chunk
    const __hip_bfloat16* Ag = Qh + (mB + w * 16 + lr8) * 512 + kcs * 8;
    const __hip_bfloat16* Bg = Kh + (nB + w * 32 + lr8) * 512 + kcs * 8;
    __hip_bfloat16* Al = As + (w * 16) * 64 + lane * 8;
    __hip_bfloat16* Bl = Bs + (w * 32) * 64 + lane * 8;
    f4 acc[4][4];
    #pragma unroll
    for (int i = 0; i < 4; ++i)
        #pragma unroll
        for (int j = 0; j < 4; ++j) acc[i][j] = f4{0.f, 0.f, 0.f, 0.f};
    int aswz = lm & 7;
    for (int kt = 0; kt < 8; ++kt) {
        __syncthreads();
        #pragma unroll
        for (int i = 0; i < 2; ++i)           // A: 8 waves x 16 rows = 128
            gl_lds16(Ag + kt * 64 + i * 8 * 512, Al + i * 8 * 64);
        #pragma unroll
        for (int i = 0; i < 4; ++i)           // B: 8 waves x 32 rows = 256
            gl_lds16(Bg + kt * 64 + i * 8 * 512, Bl + i * 8 * 64);
        __syncthreads();
        #pragma unroll
        for (int s = 0; s < 2; ++s) {
            short8 aF[4], bF[4];
            int slot = ((s * 4 + quad) ^ aswz) << 3;
            #pragma unroll
            for (int mt = 0; mt < 4; ++mt)
                aF[mt] = *(const short8*)(As + (wy * 64 + mt * 16 + lm) * 64 + slot);
            #pragma unroll
            for (int nt = 0; nt < 4; ++nt)
                bF[nt] = *(const short8*)(Bs + (wx * 64 + nt * 16 + lm) * 64 + slot);
            #pragma unroll
            for (int mt = 0; mt < 4; ++mt)
                #pragma unroll
                for (int nt = 0; nt < 4; ++nt)
                    acc[mt][nt] = MFMA16(aF[mt], bF[nt], acc[mt][nt]);
        }
    }
    if (blockIdx.x < 32) {
        // full-token rows: packed atomic argmax
        #pragma unroll
        for (int mt = 0; mt < 4; ++mt)
            #pragma unroll
            for (int reg = 0; reg < 4; ++reg) {
                float bv = -FLT_MAX; int bi = 0;
                #pragma unroll
                for (int nt = 0; nt < 4; ++nt) {
                    float v = acc[mt][nt][reg];
                    int n = nB + wx * 64 + nt * 16 + lm;
                    if (v > bv) { bv = v; bi = n; }
                }
                #pragma unroll
                for (int off = 1; off < 16; off <<= 1) {
                    float ov = __shfl_xor(bv, off);
                    int oi = __shfl_xor(bi, off);
                    if (ov > bv || (ov == bv && oi < bi)) { bv = ov; bi = oi; }
                }
                if (lm == 0) {
                    unsigned ub = __float_as_uint(bv);
                    ub = (ub & 0x80000000u) ? ~ub : (ub | 0x80000000u);
                    u64 key = ((u64)ub << 32) | (u64)(0xFFFFFFFFu - (unsigned)bi);
                    int tok = mB + wy * 64 + mt * 16 + quad * 4 + reg;
                    atomicMax(&packed[tok], key);
                }
            }
    } else {
        // pooled rows: bf16 logit rows for candidate rescore
        #pragma unroll
        for (int mt = 0; mt < 4; ++mt)
            #pragma unroll
            for (int reg = 0; reg < 4; ++reg) {
                int tok = mB + wy * 64 + mt * 16 + quad * 4 + reg;
                long long base = (long long)(tok - NFULL) * 4096;
                #pragma unroll
                for (int nt = 0; nt < 4; ++nt)
                    Lp[base + nB + wx * 64 + nt * 16 + lm] =
                        __float2bfloat16(acc[mt][nt][reg]);
            }
    }
}

// ======================= tail: rescore | hist+perplexity ===================
__global__ __launch_bounds__(256) void tail_k(
    const float* __restrict__ Qpool, const float* __restrict__ Kn,
    const __hip_bfloat16* __restrict__ Lp, const unsigned int* __restrict__ Kmax2i,
    const u64* __restrict__ packed, int* __restrict__ codeP,
    float* __restrict__ outPpl) {
    __shared__ int cnt[4096];
    __shared__ float red[4];
    int tid = threadIdx.x;
    if (blockIdx.x < 256) {
        int wid = tid >> 6, lane = tid & 63;
        int tok = blockIdx.x * 4 + wid;
        const float* q = Qpool + tok * 512;
        float4 q0 = *(const float4*)(q + lane * 8);
        float4 q1 = *(const float4*)(q + lane * 8 + 4);
        float qs = q0.x * q0.x + q0.y * q0.y + q0.z * q0.z + q0.w * q0.w +
                   q1.x * q1.x + q1.y * q1.y + q1.z * q1.z + q1.w * q1.w;
        #pragma unroll
        for (int o = 32; o > 0; o >>= 1) qs += __shfl_xor(qs, o);
        float delta = 0.0078125f * sqrtf(qs) * sqrtf(__uint_as_float(*Kmax2i));
        const __hip_bfloat16* row = Lp + (long long)tok * 4096;
        float mx = -FLT_MAX;
        for (int c = 0; c < 64; ++c)
            mx = fmaxf(mx, __bfloat162float(row[c * 64 + lane]));
        #pragma unroll
        for (int o = 32; o > 0; o >>= 1) mx = fmaxf(mx, __shfl_xor(mx, o));
        float thr = mx - delta;
        float bv = -FLT_MAX; int bi = 0;
        for (int c = 0; c < 64; ++c) {
            float v = __bfloat162float(row[c * 64 + lane]);
            u64 mask = __ballot(v >= thr);
            while (mask) {
                int l = __ffsll((long long)mask) - 1;
                mask &= mask - 1;
                int n = c * 64 + l;
                const float* k = Kn + n * 512;
                float4 k0 = *(const float4*)(k + lane * 8);
                float4 k1 = *(const float4*)(k + lane * 8 + 4);
                float d = q0.x * k0.x;
                d = fmaf(q0.y, k0.y, d); d = fmaf(q0.z, k0.z, d); d = fmaf(q0.w, k0.w, d);
                d = fmaf(q1.x, k1.x, d); d = fmaf(q1.y, k1.y, d);
                d = fmaf(q1.z, k1.z, d); d = fmaf(q1.w, k1.w, d);
                #pragma unroll
                for (int o = 32; o > 0; o >>= 1) d += __shfl_xor(d, o);
                if (d > bv) { bv = d; bi = n; }   // ascending n => first-max wins
            }
        }
        if (lane == 0) codeP[tok] = bi;
    } else {
        for (int i = tid; i < 4096; i += 256) cnt[i] = 0;
        __syncthreads();
        for (int i = tid; i < 4096; i += 256) {
            int bi = (int)(0xFFFFFFFFu - (unsigned)(packed[i] & 0xFFFFFFFFu));
            atomicAdd(&cnt[bi], 1);
        }
        __syncthreads();
        float s = 0.f;
        for (int i = tid; i < 4096; i += 256) {
            float p = (float)cnt[i] * (1.0f / 4096.0f);
            s += p * logf(p + 1e-7f);
        }
        #pragma unroll
        for (int o = 32; o > 0; o >>= 1) s += __shfl_xor(s, o);
        if ((tid & 63) == 0) red[tid >> 6] = s;
        __syncthreads();
        if (tid == 0)
            outPpl[0] = expf(-(red[0] + red[1] + red[2] + red[3]));
    }
}

// ======================= z_hat: wave per (b, j) ============================
__global__ void zhat_k(const float* __restrict__ Vv, const int* __restrict__ codeP,
                       float* __restrict__ out) {
    int w = (blockIdx.x << 2) + (threadIdx.x >> 6);   // 0..1023
    int lane = threadIdx.x & 63;
    int b = w >> 8, j = w & 255;
    const int* cb = codeP + (b << 8);
    const float* rm = Vv + cb[max(j - 1, 0)] * 512;
    const float* r0 = Vv + cb[j] * 512;
    const float* rp = Vv + cb[min(j + 1, 255)] * 512;
    #pragma unroll
    for (int i = 0; i < 8; ++i) {
        int c = i * 64 + lane;
        float vm = rm[c], v0 = r0[c], vp = rp[c];
        float4 o;
        o.x = 0.375f * vm + 0.625f * v0;
        o.y = 0.125f * vm + 0.875f * v0;
        o.z = 0.875f * v0 + 0.125f * vp;
        o.w = 0.625f * v0 + 0.375f * vp;
        *(float4*)&out[(((b << 9) + c) << 10) + (j << 2)] = o;
    }
}

extern "C" void kernel_launch(void* const* d_in, const int* in_sizes, int n_in,
                              void* d_out, int out_size, void* d_ws, size_t ws_size,
                              hipStream_t stream) {
    const float* z   = (const float*)d_in[0];
    const float* cbk = (const float*)d_in[2];
    const float* Wq  = (const float*)d_in[3];
    const float* bq  = (const float*)d_in[4];
    const float* Wk  = (const float*)d_in[5];
    const float* bk  = (const float*)d_in[6];
    const float* Wv  = (const float*)d_in[7];
    const float* bv  = (const float*)d_in[8];
    const float* Wp  = (const float*)d_in[9];
    const float* bp  = (const float*)d_in[10];
    const float* gq  = (const float*)d_in[11];
    const float* gk  = (const float*)d_in[12];
    float* out = (float*)d_out;

    // ---- workspace layout ----
    float* X      = (float*)d_ws;            // 5120*512 (rows 0..4095 = P3 alias)
    float* Qpool  = X + 5120 * 512;          // 1024*512
    float* Kn     = Qpool + 1024 * 512;      // 4096*512 (doubles as P2)
    float* Vb     = Kn + 4096 * 512;         // 4096*512
    float* Cp     = Vb + 4096 * 512;         // 5120*8
    float* P0     = Cp + 5120 * 8;           // 5120*512 (aliased by Lp later)
    float* P1     = P0 + 5120 * 512;         // 5120*512
    u64*   packed = (u64*)(P1 + 5120 * 512); // 4096
    unsigned int* Kmax2i = (unsigned int*)(packed + 4096);  // 4
    int*   codeP  = (int*)(Kmax2i + 4);      // 1024
    __hip_bfloat16* Qh  = (__hip_bfloat16*)(codeP + 1024);  // 5120*512
    __hip_bfloat16* Kh  = Qh + 5120 * 512;   // 4096*512
    __hip_bfloat16* Xh  = Kh + 4096 * 512;   // 4096*512
    __hip_bfloat16* cbh = Xh + 4096 * 512;   // 4096*512
    __hip_bfloat16* WqT = cbh + 4096 * 512;  // 512*512
    __hip_bfloat16* WvT = WqT + 512 * 512;   // 512*512
    __hip_bfloat16* Lp  = (__hip_bfloat16*)P0;  // alias: 1024*4096 bf16
    float* P2 = Kn;                          // alias: K-rows only (0..4095)
    float* P3 = X;                           // alias: X rows 0..4095 are dead

    prep_k<<<4624, 256, 0, stream>>>(z, cbk, Wq, Wv, X, Xh, cbh, WqT, WvT,
                                     packed, Kmax2i);
    mid1_k<<<2432, 256, 0, stream>>>(Xh, cbk, X + 4096 * 512, Wk, Wq, Wp, bp,
                                     P0, P1, P2, P3, Cp);
    mid2_k<<<1536, 256, 0, stream>>>(Xh, WqT, cbh, WvT, P0, P1, P2, P3,
                                     bk, bq, gk, gq, Cp, bv,
                                     Qh, Vb, Kn, Kh, Qpool, Kmax2i);
    logits_full_k<<<dim3(40, 16), 512, 0, stream>>>(Qh, Kh, packed, Lp);
    tail_k<<<257, 256, 0, stream>>>(Qpool, Kn, Lp, Kmax2i, packed, codeP,
                                    out + 4 * 512 * 1024);
    zhat_k<<<256, 256, 0, stream>>>(Vb, codeP, out);
}

// Round 13
// 202.295 us; speedup vs baseline: 1.1699x; 1.0894x over previous
//
#include <hip/hip_runtime.h>
#include <hip/hip_bf16.h>
#include <cfloat>
#include <math.h>

#define NFULL 4096
#define NPOOL 1024
#define NTOK  5120
#define VDIM  4096

typedef __attribute__((ext_vector_type(8))) short short8;   // 8 bf16 (4 VGPR)
typedef __attribute__((ext_vector_type(4))) float f4;       // MFMA acc
typedef unsigned long long u64;

#define MFMA16(a,b,c) __builtin_amdgcn_mfma_f32_16x16x32_bf16((a),(b),(c),0,0,0)

static __device__ __forceinline__ void gl_lds16(const void* g, void* l) {
    __builtin_amdgcn_global_load_lds(
        (const __attribute__((address_space(1))) unsigned int*)g,
        (__attribute__((address_space(3))) unsigned int*)l, 16, 0, 0);
}

// ==== bf16 MFMA 128x128 core, BK=64, XOR-swizzled LDS (r4-verified) ========
#define BGEMM3_CORE(AM, Bt)                                                    \
    int lane = tid & 63, w = tid >> 6, wy = w >> 1, wx = w & 1;                \
    int lm = lane & 15, quad = lane >> 4;                                      \
    int lr8 = lane >> 3;                                                       \
    int kcs = (lane & 7) ^ lr8;                                                \
    int rS = w * 32 + lr8;                                                     \
    const __hip_bfloat16* Ag = (AM) + (mB + rS) * 512 + kcs * 8;               \
    const __hip_bfloat16* Bg = (Bt) + (nB + rS) * 512 + kcs * 8;               \
    __hip_bfloat16* Al = As + (w * 32) * 64 + lane * 8;                        \
    __hip_bfloat16* Bl = Bs + (w * 32) * 64 + lane * 8;                        \
    f4 acc[4][4];                                                              \
    _Pragma("unroll") for (int i = 0; i < 4; ++i)                              \
        _Pragma("unroll") for (int j = 0; j < 4; ++j)                          \
            acc[i][j] = f4{0.f, 0.f, 0.f, 0.f};                                \
    int aswz = lm & 7;                                                         \
    for (int kt = 0; kt < 8; ++kt) {                                           \
        __syncthreads();                                                       \
        _Pragma("unroll") for (int i = 0; i < 4; ++i) {                        \
            gl_lds16(Ag + kt * 64 + i * 8 * 512, Al + i * 8 * 64);             \
            gl_lds16(Bg + kt * 64 + i * 8 * 512, Bl + i * 8 * 64);             \
        }                                                                      \
        __syncthreads();                                                       \
        _Pragma("unroll") for (int s = 0; s < 2; ++s) {                        \
            short8 aF[4], bF[4];                                               \
            int slot = ((s * 4 + quad) ^ aswz) << 3;                           \
            _Pragma("unroll") for (int mt = 0; mt < 4; ++mt)                   \
                aF[mt] = *(const short8*)(As + (wy * 64 + mt * 16 + lm) * 64 + slot); \
            _Pragma("unroll") for (int nt = 0; nt < 4; ++nt)                   \
                bF[nt] = *(const short8*)(Bs + (wx * 64 + nt * 16 + lm) * 64 + slot); \
            _Pragma("unroll") for (int mt = 0; mt < 4; ++mt)                   \
                _Pragma("unroll") for (int nt = 0; nt < 4; ++nt)               \
                    acc[mt][nt] = MFMA16(aF[mt], bF[nt], acc[mt][nt]);         \
        }                                                                      \
    }

// ======================= prep: transposes + casts + zero-init ==============
// r22: also emits bf16 hi/lo splits for the bf16x3 MFMA projection:
//   cbl (codebook lo), Xph/Xpl (pooled-X hi/lo), WkTh/WkTl, WqTl.
// All live in the dead X rows 0..4095 region (P3 eliminated).
__global__ void prep_k(const float* __restrict__ z, const float* __restrict__ cbk,
                       const float* __restrict__ Wq, const float* __restrict__ Wv,
                       const float* __restrict__ Wk,
                       float* __restrict__ X, __hip_bfloat16* __restrict__ Xh,
                       __hip_bfloat16* __restrict__ cbh, __hip_bfloat16* __restrict__ cbl,
                       __hip_bfloat16* __restrict__ Xph, __hip_bfloat16* __restrict__ Xpl,
                       __hip_bfloat16* __restrict__ WqT, __hip_bfloat16* __restrict__ WqTl,
                       __hip_bfloat16* __restrict__ WvT,
                       __hip_bfloat16* __restrict__ WkTh, __hip_bfloat16* __restrict__ WkTl,
                       u64* __restrict__ packed, unsigned int* __restrict__ Kmax2i) {
    __shared__ float smem[33 * 32];
    int bx = blockIdx.x;
    if (bx < 2048) {
        float (*tile)[33] = (float(*)[33])smem;
        int t0 = (bx & 31) * 32, c0 = ((bx >> 5) & 15) * 32, b = bx >> 9;
        int tx = threadIdx.x & 31, ty = threadIdx.x >> 5;
        #pragma unroll
        for (int i = 0; i < 4; ++i) {
            int c = ty + i * 8;
            tile[c][tx] = z[((b << 9) + c0 + c) * 1024 + t0 + tx];
        }
        __syncthreads();
        #pragma unroll
        for (int i = 0; i < 4; ++i) {
            int tl = ty + i * 8;
            int tok = (b << 10) + t0 + tl;
            Xh[tok * 512 + c0 + tx] = __float2bfloat16(tile[tx][tl]);
        }
        float m = 0.25f * (tile[tx][ty * 4] + tile[tx][ty * 4 + 1] +
                           tile[tx][ty * 4 + 2] + tile[tx][ty * 4 + 3]);
        int tq = (t0 >> 2) + ty;
        int prow = (b << 8) + tq;
        X[(NFULL + prow) * 512 + c0 + tx] = m;
        __hip_bfloat16 mh = __float2bfloat16(m);
        Xph[prow * 512 + c0 + tx] = mh;
        Xpl[prow * 512 + c0 + tx] = __float2bfloat16(m - __bfloat162float(mh));
    } else if (bx < 4096) {
        int i0 = (bx - 2048) * 1024 + threadIdx.x * 4;
        float4 v = *(const float4*)(cbk + i0);
        __hip_bfloat16* d = cbh + i0;
        __hip_bfloat16* dl = cbl + i0;
        float vv[4] = {v.x, v.y, v.z, v.w};
        #pragma unroll
        for (int j = 0; j < 4; ++j) {
            __hip_bfloat16 h = __float2bfloat16(vv[j]);
            d[j] = h;
            dl[j] = __float2bfloat16(vv[j] - __bfloat162float(h));
        }
    } else if (bx < 4864) {
        int lin = bx - 4096;                   // 0..767: Wq | Wv | Wk
        int sel = lin >> 8;
        const float* W = (sel == 0) ? Wq : (sel == 1) ? Wv : Wk;
        float (*t)[33] = (float(*)[33])smem;
        int bk = ((lin >> 4) & 15) * 32, bn = (lin & 15) * 32;
        int lx = threadIdx.x & 31, ly = threadIdx.x >> 5;
        #pragma unroll
        for (int i = 0; i < 4; ++i) {
            int r = ly * 4 + i;
            t[r][lx] = W[(bk + r) * 512 + bn + lx];
        }
        __syncthreads();
        #pragma unroll
        for (int i = 0; i < 4; ++i) {
            int r = ly * 4 + i;
            float v = t[lx][r];
            int idx = (bn + r) * 512 + bk + lx;
            __hip_bfloat16 h = __float2bfloat16(v);
            if (sel == 0) {
                WqT[idx] = h;
                WqTl[idx] = __float2bfloat16(v - __bfloat162float(h));
            } else if (sel == 1) {
                WvT[idx] = h;
            } else {
                WkTh[idx] = h;
                WkTl[idx] = __float2bfloat16(v - __bfloat162float(h));
            }
        }
    } else {
        int i = (bx - 4864) * 256 + threadIdx.x;     // 0..4095
        packed[i] = 0ull;
        if (bx == 4864 && threadIdx.x == 0) Kmax2i[0] = 0u;
    }
}

// ======================= mid1: bf16x3 MFMA proj | pool-c ===================
// r22: fp32 VALU GEMM (45.5us, LDS-pipe bound; 8x8 fix allocator-blocked
// r18-r20) replaced by bf16x3 MFMA emulation: Ah.Bh + Ah.Bl + Al.Bh with
// fp32-accumulating MFMA (error ~2^-17 rel -- ~5x the fp32 reassociation
// error the kernel already carries, 100x finer than the bf16 logits the
// rescore corrects).  Three K=512 passes = exactly BGEMM3_CORE, mapped on
// split-K plumbing: part0->P0, part1->P1, part2->P2 (=Kn for K rows,
// =Qpool-4096*512 for Q rows; read-before-write in mid2).  8.05 GFLOP of
// MFMA ~ 20us vs 45.5 on the VALU.  Cp branch untouched.
__global__ __launch_bounds__(256) void mid1_k(
    const __hip_bfloat16* __restrict__ Xh,
    const __hip_bfloat16* __restrict__ cbh, const __hip_bfloat16* __restrict__ cbl,
    const __hip_bfloat16* __restrict__ Xph, const __hip_bfloat16* __restrict__ Xpl,
    const __hip_bfloat16* __restrict__ WkTh, const __hip_bfloat16* __restrict__ WkTl,
    const __hip_bfloat16* __restrict__ WqT, const __hip_bfloat16* __restrict__ WqTl,
    const float* __restrict__ Xp,
    const float* __restrict__ Wp, const float* __restrict__ bp,
    float* __restrict__ P0, float* __restrict__ P1,
    float* P2, float* P2q,
    float* __restrict__ Cp) {
    __shared__ __align__(16) char smraw[32768];
    int bx = blockIdx.x, tid = threadIdx.x;
    if (bx < 480) {
        const __hip_bfloat16 *AM, *Bt; float* P;
        int mB, nB;
        if (bx < 384) {
            // codebook (K) rows: 3 parts x (32 m-tiles x 4 n-tiles)
            int part = bx >> 7, rem = bx & 127;
            mB = (rem & 31) * 128; nB = (rem >> 5) * 128;
            AM = (part == 2) ? cbl : cbh;
            Bt = (part == 1) ? WkTl : WkTh;
            P  = (part == 0) ? P0 : (part == 1) ? P1 : P2;
        } else {
            // pooled-Q rows: 3 parts x (8 m-tiles x 4 n-tiles)
            int lin = bx - 384;
            int part = lin >> 5, rem = lin & 31;
            mB = NFULL + (rem & 7) * 128; nB = (rem >> 3) * 128;
            AM = ((part == 2) ? Xpl : Xph) - NFULL * 512;
            Bt = (part == 1) ? WqTl : WqT;
            P  = (part == 0) ? P0 : (part == 1) ? P1 : P2q;
        }
        __hip_bfloat16* As = (__hip_bfloat16*)smraw;
        __hip_bfloat16* Bs = As + 128 * 64;
        BGEMM3_CORE(AM, Bt)
        #pragma unroll
        for (int mt = 0; mt < 4; ++mt)
            #pragma unroll
            for (int reg = 0; reg < 4; ++reg) {
                int m = mB + wy * 64 + mt * 16 + quad * 4 + reg;
                #pragma unroll
                for (int nt = 0; nt < 4; ++nt)
                    P[m * 512 + nB + wx * 64 + nt * 16 + lm] = acc[mt][nt][reg];
            }
    } else {
        // ---------------- head-pool weights Cp ------------------------------
        float* Wl = (float*)smraw;             // 4160 floats: lane stride 65
        for (int i = tid; i < 4096; i += 256) Wl[i + (i >> 6)] = Wp[i];
        __syncthreads();
        int w = tid >> 6, lane = tid & 63;
        int tok = (bx - 480) * 4 + w;          // 0..5119
        float x[8];
        if (tok < NFULL) {
            short8 xv = *(const short8*)(Xh + tok * 512 + lane * 8);
            #pragma unroll
            for (int j = 0; j < 8; ++j)
                x[j] = __uint_as_float(((unsigned)(unsigned short)xv[j]) << 16);
        } else {
            const float* xp = Xp + (tok - NFULL) * 512 + lane * 8;
            float4 a = *(const float4*)xp, b = *(const float4*)(xp + 4);
            x[0] = a.x; x[1] = a.y; x[2] = a.z; x[3] = a.w;
            x[4] = b.x; x[5] = b.y; x[6] = b.z; x[7] = b.w;
        }
        float s[8] = {};
        int base = lane * 65;
        #pragma unroll
        for (int j = 0; j < 8; ++j)
            #pragma unroll
            for (int h = 0; h < 8; ++h)
                s[h] = fmaf(x[j], Wl[base + j * 8 + h], s[h]);
        #pragma unroll
        for (int h = 0; h < 8; ++h)
            #pragma unroll
            for (int o = 32; o > 0; o >>= 1) s[h] += __shfl_xor(s[h], o);
        if (lane == 0) {
            #pragma unroll
            for (int h = 0; h < 8; ++h) Cp[tok * 8 + h] = s[h] + bp[h];
        }
    }
}

// ======================= mid2: bf16 bgemms | split-K norm-finish ===========
// [0,256): MFMA GEMMs.  [256,1536): norm-finish, wave-per-row, 4 rows/blk.
// All rows reduce P0+P1+third where third = P2 (=Kn) for K rows, P2q
// (=Qpool-4096*512) for Q rows.  Read-before-write per row -- NO
// __restrict__ on P2/P2q/Kn/Qpool.
__global__ __launch_bounds__(256) void mid2_k(
    const __hip_bfloat16* __restrict__ Xh, const __hip_bfloat16* __restrict__ WqT,
    const __hip_bfloat16* __restrict__ cbh, const __hip_bfloat16* __restrict__ WvT,
    const float* __restrict__ P0, const float* __restrict__ P1,
    const float* P2, const float* P2q,
    const float* __restrict__ bk, const float* __restrict__ bq,
    const float* __restrict__ gk, const float* __restrict__ gq,
    const float* __restrict__ Cp, const float* __restrict__ bvv,
    __hip_bfloat16* __restrict__ Qh, float* __restrict__ Vb,
    float* Kn, __hip_bfloat16* __restrict__ Kh,
    float* Qpool, unsigned int* __restrict__ Kmax2i) {
    __shared__ __align__(16) char smraw[32768];
    int bx = blockIdx.x, tid = threadIdx.x;
    if (bx < 256) {
        int part = bx >> 7, rem = bx & 127;
        int mB = (rem & 31) * 128, nB = (rem >> 5) * 128;
        const __hip_bfloat16* AM = part ? cbh : Xh;
        const __hip_bfloat16* Bt = part ? WvT : WqT;
        __hip_bfloat16* As = (__hip_bfloat16*)smraw;
        __hip_bfloat16* Bs = As + 128 * 64;
        BGEMM3_CORE(AM, Bt)
        if (part == 0) {
            int h = (rem >> 5) * 2 + wx;
            float bb[4], gg[4];
            #pragma unroll
            for (int nt = 0; nt < 4; ++nt) {
                bb[nt] = bq[h * 64 + nt * 16 + lm];
                gg[nt] = gq[nt * 16 + lm];
            }
            #pragma unroll
            for (int mt = 0; mt < 4; ++mt)
                #pragma unroll
                for (int reg = 0; reg < 4; ++reg) {
                    int tok = mB + wy * 64 + mt * 16 + quad * 4 + reg;
                    float vv[4], ss = 0.f;
                    #pragma unroll
                    for (int nt = 0; nt < 4; ++nt) {
                        vv[nt] = acc[mt][nt][reg] + bb[nt];
                        ss = fmaf(vv[nt], vv[nt], ss);
                    }
                    #pragma unroll
                    for (int off = 1; off < 16; off <<= 1) ss += __shfl_xor(ss, off);
                    float sc = rsqrtf(ss * (1.0f / 64.0f) + 1e-5f) *
                               Cp[tok * 8 + h] * 0.04419417382415922f;  // 1/(8*sqrt8)
                    #pragma unroll
                    for (int nt = 0; nt < 4; ++nt)
                        Qh[tok * 512 + h * 64 + nt * 16 + lm] =
                            __float2bfloat16(vv[nt] * sc * gg[nt]);
                }
        } else {
            float bb[4];
            #pragma unroll
            for (int nt = 0; nt < 4; ++nt) bb[nt] = bvv[nB + wx * 64 + nt * 16 + lm];
            #pragma unroll
            for (int mt = 0; mt < 4; ++mt)
                #pragma unroll
                for (int reg = 0; reg < 4; ++reg) {
                    int m = mB + wy * 64 + mt * 16 + quad * 4 + reg;
                    #pragma unroll
                    for (int nt = 0; nt < 4; ++nt)
                        Vb[m * 512 + nB + wx * 64 + nt * 16 + lm] =
                            acc[mt][nt][reg] + bb[nt];
                }
        }
    } else {
        // ---------------- 3-way split reduce + rmsnorm (wave-per-row) -------
        int w = tid >> 6, lane = tid & 63;
        int row = (bx - 256) * 4 + w;      // 0..5119
        bool isQ = row >= NFULL;
        const float* bias = isQ ? bq : bk;
        const float* g = isQ ? gq : gk;
        int c0 = lane * 8;                 // 8 contiguous cols per lane
        const float* p0 = P0 + row * 512 + c0;
        const float* p1 = P1 + row * 512 + c0;
        const float* p2 = (isQ ? P2q : P2) + row * 512 + c0;
        float4 a0 = *(const float4*)p0,  a1 = *(const float4*)(p0 + 4);
        float4 d0 = *(const float4*)p1,  d1 = *(const float4*)(p1 + 4);
        float4 x0 = *(const float4*)p2,  x1 = *(const float4*)(p2 + 4);
        float4 e0 = *(const float4*)(bias + c0), e1 = *(const float4*)(bias + c0 + 4);
        int gi = (lane & 7) * 8;
        float4 g0 = *(const float4*)(g + gi), g1 = *(const float4*)(g + gi + 4);
        float v[8];
        v[0] = a0.x + d0.x + x0.x + e0.x; v[1] = a0.y + d0.y + x0.y + e0.y;
        v[2] = a0.z + d0.z + x0.z + e0.z; v[3] = a0.w + d0.w + x0.w + e0.w;
        v[4] = a1.x + d1.x + x1.x + e1.x; v[5] = a1.y + d1.y + x1.y + e1.y;
        v[6] = a1.z + d1.z + x1.z + e1.z; v[7] = a1.w + d1.w + x1.w + e1.w;
        // per-head (64-col) sum-of-squares: 8 lanes per head
        float ss = 0.f;
        #pragma unroll
        for (int j = 0; j < 8; ++j) ss = fmaf(v[j], v[j], ss);
        ss += __shfl_xor(ss, 1); ss += __shfl_xor(ss, 2); ss += __shfl_xor(ss, 4);
        float sc = rsqrtf(ss * (1.0f / 64.0f) + 1e-5f);
        float gg[8] = {g0.x, g0.y, g0.z, g0.w, g1.x, g1.y, g1.z, g1.w};
        float o_[8];
        #pragma unroll
        for (int j = 0; j < 8; ++j) o_[j] = v[j] * sc * gg[j];
        if (isQ) {
            float cf = Cp[row * 8 + (lane >> 3)] * 0.04419417382415922f;
            #pragma unroll
            for (int j = 0; j < 8; ++j) o_[j] *= cf;
            float* qp = Qpool + (row - NFULL) * 512 + c0;
            *(float4*)qp       = make_float4(o_[0], o_[1], o_[2], o_[3]);
            *(float4*)(qp + 4) = make_float4(o_[4], o_[5], o_[6], o_[7]);
            __hip_bfloat16 hb[8];
            #pragma unroll
            for (int j = 0; j < 8; ++j) hb[j] = __float2bfloat16(o_[j]);
            *(short8*)(Qh + row * 512 + c0) = *(const short8*)hb;
        } else {
            float* kp = Kn + row * 512 + c0;
            *(float4*)kp       = make_float4(o_[0], o_[1], o_[2], o_[3]);
            *(float4*)(kp + 4) = make_float4(o_[4], o_[5], o_[6], o_[7]);
            __hip_bfloat16 hb[8];
            #pragma unroll
            for (int j = 0; j < 8; ++j) hb[j] = __float2bfloat16(o_[j]);
            *(short8*)(Kh + row * 512 + c0) = *(const short8*)hb;
            float rs = 0.f;
            #pragma unroll
            for (int j = 0; j < 8; ++j) rs = fmaf(o_[j], o_[j], rs);
            #pragma unroll
            for (int o = 32; o > 0; o >>= 1) rs += __shfl_xor(rs, o);
            float* wsum = (float*)smraw;
            if (lane == 0) wsum[w] = rs;
            __syncthreads();
            if (tid == 0) {
                float m01 = fmaxf(wsum[0], wsum[1]);
                float m23 = fmaxf(wsum[2], wsum[3]);
                atomicMax(Kmax2i, __float_as_uint(fmaxf(m01, m23)));
            }
        }
    }
}

// ==== logits over all 5120 tokens ==========================================
// r16: ASYMMETRIC 128x256 tile, BK=64, 512 threads (8 waves, 2m x 4n,
// per-wave 64x64 -> acc[4][4]).  Verified winner (logits left top-5).
__global__ __launch_bounds__(512, 4) void logits_full_k(
    const __hip_bfloat16* __restrict__ Qh, const __hip_bfloat16* __restrict__ Kh,
    u64* __restrict__ packed, __hip_bfloat16* __restrict__ Lp) {
    __shared__ __hip_bfloat16 As[128 * 64];   // 16 KB
    __shared__ __hip_bfloat16 Bs[256 * 64];   // 32 KB
    int tid = threadIdx.x;
    int mB = blockIdx.x * 128, nB = blockIdx.y * 256;   // grid (40, 16)
    int lane = tid & 63, w = tid >> 6;        // 8 waves
    int wy = w >> 2, wx = w & 3;              // wy: m-half (64), wx: n-quarter (64)
    int lm = lane & 15, quad = lane >> 4;
    int lr8 = lane >> 3;
    int kcs = (lane & 7) ^ lr8;               // XOR-swizzled source col-chunk
    const __hip_bfloat16* Ag = Qh + (mB + w * 16 + lr8) * 512 + kcs * 8;
    const __hip_bfloat16* Bg = Kh + (nB + w * 32 + lr8) * 512 + kcs * 8;
    __hip_bfloat16* Al = As + (w * 16) * 64 + lane * 8;
    __hip_bfloat16* Bl = Bs + (w * 32) * 64 + lane * 8;
    f4 acc[4][4];
    #pragma unroll
    for (int i = 0; i < 4; ++i)
        #pragma unroll
        for (int j = 0; j < 4; ++j) acc[i][j] = f4{0.f, 0.f, 0.f, 0.f};
    int aswz = lm & 7;
    for (int kt = 0; kt < 8; ++kt) {
        __syncthreads();
        #pragma unroll
        for (int i = 0; i < 2; ++i)           // A: 8 waves x 16 rows = 128
            gl_lds16(Ag + kt * 64 + i * 8 * 512, Al + i * 8 * 64);
        #pragma unroll
        for (int i = 0; i < 4; ++i)           // B: 8 waves x 32 rows = 256
            gl_lds16(Bg + kt * 64 + i * 8 * 512, Bl + i * 8 * 64);
        __syncthreads();
        #pragma unroll
        for (int s = 0; s < 2; ++s) {
            short8 aF[4], bF[4];
            int slot = ((s * 4 + quad) ^ aswz) << 3;
            #pragma unroll
            for (int mt = 0; mt < 4; ++mt)
                aF[mt] = *(const short8*)(As + (wy * 64 + mt * 16 + lm) * 64 + slot);
            #pragma unroll
            for (int nt = 0; nt < 4; ++nt)
                bF[nt] = *(const short8*)(Bs + (wx * 64 + nt * 16 + lm) * 64 + slot);
            #pragma unroll
            for (int mt = 0; mt < 4; ++mt)
                #pragma unroll
                for (int nt = 0; nt < 4; ++nt)
                    acc[mt][nt] = MFMA16(aF[mt], bF[nt], acc[mt][nt]);
        }
    }
    if (blockIdx.x < 32) {
        // full-token rows: packed atomic argmax
        #pragma unroll
        for (int mt = 0; mt < 4; ++mt)
            #pragma unroll
            for (int reg = 0; reg < 4; ++reg) {
                float bv = -FLT_MAX; int bi = 0;
                #pragma unroll
                for (int nt = 0; nt < 4; ++nt) {
                    float v = acc[mt][nt][reg];
                    int n = nB + wx * 64 + nt * 16 + lm;
                    if (v > bv) { bv = v; bi = n; }
                }
                #pragma unroll
                for (int off = 1; off < 16; off <<= 1) {
                    float ov = __shfl_xor(bv, off);
                    int oi = __shfl_xor(bi, off);
                    if (ov > bv || (ov == bv && oi < bi)) { bv = ov; bi = oi; }
                }
                if (lm == 0) {
                    unsigned ub = __float_as_uint(bv);
                    ub = (ub & 0x80000000u) ? ~ub : (ub | 0x80000000u);
                    u64 key = ((u64)ub << 32) | (u64)(0xFFFFFFFFu - (unsigned)bi);
                    int tok = mB + wy * 64 + mt * 16 + quad * 4 + reg;
                    atomicMax(&packed[tok], key);
                }
            }
    } else {
        // pooled rows: bf16 logit rows for candidate rescore
        #pragma unroll
        for (int mt = 0; mt < 4; ++mt)
            #pragma unroll
            for (int reg = 0; reg < 4; ++reg) {
                int tok = mB + wy * 64 + mt * 16 + quad * 4 + reg;
                long long base = (long long)(tok - NFULL) * 4096;
                #pragma unroll
                for (int nt = 0; nt < 4; ++nt)
                    Lp[base + nB + wx * 64 + nt * 16 + lm] =
                        __float2bfloat16(acc[mt][nt][reg]);
            }
    }
}

// ======================= tail: rescore | hist+perplexity ===================
__global__ __launch_bounds__(256) void tail_k(
    const float* __restrict__ Qpool, const float* __restrict__ Kn,
    const __hip_bfloat16* __restrict__ Lp, const unsigned int* __restrict__ Kmax2i,
    const u64* __restrict__ packed, int* __restrict__ codeP,
    float* __restrict__ outPpl) {
    __shared__ int cnt[4096];
    __shared__ float red[4];
    int tid = threadIdx.x;
    if (blockIdx.x < 256) {
        int wid = tid >> 6, lane = tid & 63;
        int tok = blockIdx.x * 4 + wid;
        const float* q = Qpool + tok * 512;
        float4 q0 = *(const float4*)(q + lane * 8);
        float4 q1 = *(const float4*)(q + lane * 8 + 4);
        float qs = q0.x * q0.x + q0.y * q0.y + q0.z * q0.z + q0.w * q0.w +
                   q1.x * q1.x + q1.y * q1.y + q1.z * q1.z + q1.w * q1.w;
        #pragma unroll
        for (int o = 32; o > 0; o >>= 1) qs += __shfl_xor(qs, o);
        float delta = 0.0078125f * sqrtf(qs) * sqrtf(__uint_as_float(*Kmax2i));
        const __hip_bfloat16* row = Lp + (long long)tok * 4096;
        float mx = -FLT_MAX;
        for (int c = 0; c < 64; ++c)
            mx = fmaxf(mx, __bfloat162float(row[c * 64 + lane]));
        #pragma unroll
        for (int o = 32; o > 0; o >>= 1) mx = fmaxf(mx, __shfl_xor(mx, o));
        float thr = mx - delta;
        float bv = -FLT_MAX; int bi = 0;
        for (int c = 0; c < 64; ++c) {
            float v = __bfloat162float(row[c * 64 + lane]);
            u64 mask = __ballot(v >= thr);
            while (mask) {
                int l = __ffsll((long long)mask) - 1;
                mask &= mask - 1;
                int n = c * 64 + l;
                const float* k = Kn + n * 512;
                float4 k0 = *(const float4*)(k + lane * 8);
                float4 k1 = *(const float4*)(k + lane * 8 + 4);
                float d = q0.x * k0.x;
                d = fmaf(q0.y, k0.y, d); d = fmaf(q0.z, k0.z, d); d = fmaf(q0.w, k0.w, d);
                d = fmaf(q1.x, k1.x, d); d = fmaf(q1.y, k1.y, d);
                d = fmaf(q1.z, k1.z, d); d = fmaf(q1.w, k1.w, d);
                #pragma unroll
                for (int o = 32; o > 0; o >>= 1) d += __shfl_xor(d, o);
                if (d > bv) { bv = d; bi = n; }   // ascending n => first-max wins
            }
        }
        if (lane == 0) codeP[tok] = bi;
    } else {
        for (int i = tid; i < 4096; i += 256) cnt[i] = 0;
        __syncthreads();
        for (int i = tid; i < 4096; i += 256) {
            int bi = (int)(0xFFFFFFFFu - (unsigned)(packed[i] & 0xFFFFFFFFu));
            atomicAdd(&cnt[bi], 1);
        }
        __syncthreads();
        float s = 0.f;
        for (int i = tid; i < 4096; i += 256) {
            float p = (float)cnt[i] * (1.0f / 4096.0f);
            s += p * logf(p + 1e-7f);
        }
        #pragma unroll
        for (int o = 32; o > 0; o >>= 1) s += __shfl_xor(s, o);
        if ((tid & 63) == 0) red[tid >> 6] = s;
        __syncthreads();
        if (tid == 0)
            outPpl[0] = expf(-(red[0] + red[1] + red[2] + red[3]));
    }
}

// ======================= z_hat: wave per (b, j) ============================
__global__ void zhat_k(const float* __restrict__ Vv, const int* __restrict__ codeP,
                       float* __restrict__ out) {
    int w = (blockIdx.x << 2) + (threadIdx.x >> 6);   // 0..1023
    int lane = threadIdx.x & 63;
    int b = w >> 8, j = w & 255;
    const int* cb = codeP + (b << 8);
    const float* rm = Vv + cb[max(j - 1, 0)] * 512;
    const float* r0 = Vv + cb[j] * 512;
    const float* rp = Vv + cb[min(j + 1, 255)] * 512;
    #pragma unroll
    for (int i = 0; i < 8; ++i) {
        int c = i * 64 + lane;
        float vm = rm[c], v0 = r0[c], vp = rp[c];
        float4 o;
        o.x = 0.375f * vm + 0.625f * v0;
        o.y = 0.125f * vm + 0.875f * v0;
        o.z = 0.875f * v0 + 0.125f * vp;
        o.w = 0.625f * v0 + 0.375f * vp;
        *(float4*)&out[(((b << 9) + c) << 10) + (j << 2)] = o;
    }
}

extern "C" void kernel_launch(void* const* d_in, const int* in_sizes, int n_in,
                              void* d_out, int out_size, void* d_ws, size_t ws_size,
                              hipStream_t stream) {
    const float* z   = (const float*)d_in[0];
    const float* cbk = (const float*)d_in[2];
    const float* Wq  = (const float*)d_in[3];
    const float* bq  = (const float*)d_in[4];
    const float* Wk  = (const float*)d_in[5];
    const float* bk  = (const float*)d_in[6];
    const float* Wv  = (const float*)d_in[7];
    const float* bv  = (const float*)d_in[8];
    const float* Wp  = (const float*)d_in[9];
    const float* bp  = (const float*)d_in[10];
    const float* gq  = (const float*)d_in[11];
    const float* gk  = (const float*)d_in[12];
    float* out = (float*)d_out;

    // ---- workspace layout ----
    float* X      = (float*)d_ws;            // 5120*512; rows 0..4095 host bf16x3 splits
    float* Qpool  = X + 5120 * 512;          // 1024*512 (doubles as P2 for Q rows)
    float* Kn     = Qpool + 1024 * 512;      // 4096*512 (doubles as P2 for K rows)
    float* Vb     = Kn + 4096 * 512;         // 4096*512
    float* Cp     = Vb + 4096 * 512;         // 5120*8
    float* P0     = Cp + 5120 * 8;           // 5120*512 (aliased by Lp later)
    float* P1     = P0 + 5120 * 512;         // 5120*512
    u64*   packed = (u64*)(P1 + 5120 * 512); // 4096
    unsigned int* Kmax2i = (unsigned int*)(packed + 4096);  // 4
    int*   codeP  = (int*)(Kmax2i + 4);      // 1024
    __hip_bfloat16* Qh  = (__hip_bfloat16*)(codeP + 1024);  // 5120*512
    __hip_bfloat16* Kh  = Qh + 5120 * 512;   // 4096*512
    __hip_bfloat16* Xh  = Kh + 4096 * 512;   // 4096*512
    __hip_bfloat16* cbh = Xh + 4096 * 512;   // 4096*512
    __hip_bfloat16* WqT = cbh + 4096 * 512;  // 512*512
    __hip_bfloat16* WvT = WqT + 512 * 512;   // 512*512
    __hip_bfloat16* Lp  = (__hip_bfloat16*)P0;  // alias: 1024*4096 bf16
    // bf16x3 splits in the dead X rows 0..4095 region (8.4 MB; used 7.5 MB)
    __hip_bfloat16* cbl  = (__hip_bfloat16*)X;  // 4096*512
    __hip_bfloat16* Xph  = cbl + 4096 * 512;    // 1024*512
    __hip_bfloat16* Xpl  = Xph + 1024 * 512;    // 1024*512
    __hip_bfloat16* WkTh = Xpl + 1024 * 512;    // 512*512
    __hip_bfloat16* WkTl = WkTh + 512 * 512;    // 512*512
    __hip_bfloat16* WqTl = WkTl + 512 * 512;    // 512*512
    float* P2  = Kn;                         // K-row third partial (rows 0..4095)
    float* P2q = Qpool - NFULL * 512;        // Q-row third partial (rows 4096..5119)

    prep_k<<<4880, 256, 0, stream>>>(z, cbk, Wq, Wv, Wk, X, Xh, cbh, cbl,
                                     Xph, Xpl, WqT, WqTl, WvT, WkTh, WkTl,
                                     packed, Kmax2i);
    mid1_k<<<1760, 256, 0, stream>>>(Xh, cbh, cbl, Xph, Xpl, WkTh, WkTl,
                                     WqT, WqTl, X + 4096 * 512, Wp, bp,
                                     P0, P1, P2, P2q, Cp);
    mid2_k<<<1536, 256, 0, stream>>>(Xh, WqT, cbh, WvT, P0, P1, P2, P2q,
                                     bk, bq, gk, gq, Cp, bv,
                                     Qh, Vb, Kn, Kh, Qpool, Kmax2i);
    logits_full_k<<<dim3(40, 16), 512, 0, stream>>>(Qh, Kh, packed, Lp);
    tail_k<<<257, 256, 0, stream>>>(Qpool, Kn, Lp, Kmax2i, packed, codeP,
                                    out + 4 * 512 * 1024);
    zhat_k<<<256, 256, 0, stream>>>(Vb, codeP, out);
}